// Round 1
// baseline (660.200 us; speedup 1.0000x reference)
//
#include <hip/hip_runtime.h>

typedef unsigned short u16;
typedef unsigned int uint;
typedef __attribute__((ext_vector_type(4))) float floatx4;
typedef __attribute__((ext_vector_type(16))) float floatx16;
typedef __attribute__((ext_vector_type(8))) short shortx8;

// ---------- helpers ----------
__device__ __forceinline__ u16 f2b(float f) {
    unsigned int u = __float_as_uint(f);
    unsigned int r = (u + 0x7fffu + ((u >> 16) & 1u)) >> 16;
    return (u16)r;
}
__device__ __forceinline__ float b2f(u16 u) {
    return __uint_as_float(((unsigned int)u) << 16);
}
__device__ __forceinline__ void gl_lds16(const u16* g, u16* l) {
    __builtin_amdgcn_global_load_lds(
        (const __attribute__((address_space(1))) void*)g,
        (__attribute__((address_space(3))) void*)l, 16, 0, 0);
}
__device__ __forceinline__ float gelu_f(float v) {
    float e = __expf(1.59576912f * v * (1.0f + 0.044715f * v * v));
    return v * e / (e + 1.0f);
}

// ---------- shared-memory union (64 KiB): 2 blocks/CU guaranteed ----------
struct SG16 { u16 a[2][128 * 64]; u16 b[2][128 * 64]; };   // 64 KiB
struct SG32 { u16 a[2][64 * 128]; u16 b[2][64 * 128]; };   // 64 KiB
struct SAttn {
    u16 k[128][72];
    u16 v[64][152];
    u16 p[4][16][104];
    float bias[64];
};                                                          // ~50 KiB
union SMem { SG16 g16; SG32 g32; SAttn at; };
static_assert(sizeof(SMem) == 65536, "smem union must be 64KiB");

// ---------- device-scope grid barrier (Guideline 16 pattern) ----------
// 512 blocks = exactly 2/CU (launch_bounds(256,2) + 64KiB LDS) -> all
// co-resident, spin barrier is safe. Counters zeroed by memset node.
__device__ __forceinline__ void gbar(unsigned* c, unsigned tgt) {
    __syncthreads();
    if (threadIdx.x == 0) {
        __threadfence();   // release: publish this block's writes
        __hip_atomic_fetch_add(c, 1u, __ATOMIC_RELEASE, __HIP_MEMORY_SCOPE_AGENT);
        while (__hip_atomic_load(c, __ATOMIC_ACQUIRE, __HIP_MEMORY_SCOPE_AGENT) < tgt)
            __builtin_amdgcn_s_sleep(2);
        __threadfence();   // acquire: invalidate stale L1/L2 before consuming
    }
    __syncthreads();
}

// ---------- wave-per-row LN (C=512): 8 elems/lane, shuffle-only ----------
__device__ __forceinline__ void ln_row_wave_f32(const float* __restrict__ x,
                                                const float* __restrict__ w,
                                                const float* __restrict__ b,
                                                u16* __restrict__ out, int row) {
    int lane = threadIdx.x & 63;
    const float4* xr = (const float4*)(x + (size_t)row * 512);
    float4 v0 = xr[lane * 2], v1 = xr[lane * 2 + 1];
    float s = v0.x + v0.y + v0.z + v0.w + v1.x + v1.y + v1.z + v1.w;
    float s2 = v0.x * v0.x + v0.y * v0.y + v0.z * v0.z + v0.w * v0.w +
               v1.x * v1.x + v1.y * v1.y + v1.z * v1.z + v1.w * v1.w;
    #pragma unroll
    for (int o = 32; o > 0; o >>= 1) {
        s += __shfl_xor(s, o, 64);
        s2 += __shfl_xor(s2, o, 64);
    }
    float mu = s * (1.0f / 512.0f);
    float var = s2 * (1.0f / 512.0f) - mu * mu;
    float rstd = rsqrtf(var + 1e-5f);
    const float4* wr = (const float4*)w;
    const float4* br = (const float4*)b;
    float4 w0 = wr[lane * 2], w1 = wr[lane * 2 + 1];
    float4 b0 = br[lane * 2], b1 = br[lane * 2 + 1];
    uint4 o4;
    o4.x = (uint)f2b((v0.x - mu) * rstd * w0.x + b0.x) |
           ((uint)f2b((v0.y - mu) * rstd * w0.y + b0.y) << 16);
    o4.y = (uint)f2b((v0.z - mu) * rstd * w0.z + b0.z) |
           ((uint)f2b((v0.w - mu) * rstd * w0.w + b0.w) << 16);
    o4.z = (uint)f2b((v1.x - mu) * rstd * w1.x + b1.x) |
           ((uint)f2b((v1.y - mu) * rstd * w1.y + b1.y) << 16);
    o4.w = (uint)f2b((v1.z - mu) * rstd * w1.z + b1.z) |
           ((uint)f2b((v1.w - mu) * rstd * w1.w + b1.w) << 16);
    ((uint4*)(out + (size_t)row * 512))[lane] = o4;
}

__device__ __forceinline__ void ln_row_wave_b16(const u16* __restrict__ x,
                                                const float* __restrict__ w,
                                                const float* __restrict__ b,
                                                u16* __restrict__ out, int row) {
    int lane = threadIdx.x & 63;
    uint4 p = ((const uint4*)(x + (size_t)row * 512))[lane];
    float v[8];
    v[0] = b2f((u16)(p.x & 0xffffu)); v[1] = b2f((u16)(p.x >> 16));
    v[2] = b2f((u16)(p.y & 0xffffu)); v[3] = b2f((u16)(p.y >> 16));
    v[4] = b2f((u16)(p.z & 0xffffu)); v[5] = b2f((u16)(p.z >> 16));
    v[6] = b2f((u16)(p.w & 0xffffu)); v[7] = b2f((u16)(p.w >> 16));
    float s = 0.f, s2 = 0.f;
    #pragma unroll
    for (int i = 0; i < 8; i++) { s += v[i]; s2 += v[i] * v[i]; }
    #pragma unroll
    for (int o = 32; o > 0; o >>= 1) {
        s += __shfl_xor(s, o, 64);
        s2 += __shfl_xor(s2, o, 64);
    }
    float mu = s * (1.0f / 512.0f);
    float var = s2 * (1.0f / 512.0f) - mu * mu;
    float rstd = rsqrtf(var + 1e-5f);
    const float4* wr = (const float4*)w;
    const float4* br = (const float4*)b;
    float4 w0 = wr[lane * 2], w1 = wr[lane * 2 + 1];
    float4 b0 = br[lane * 2], b1 = br[lane * 2 + 1];
    float o8[8];
    o8[0] = (v[0] - mu) * rstd * w0.x + b0.x;
    o8[1] = (v[1] - mu) * rstd * w0.y + b0.y;
    o8[2] = (v[2] - mu) * rstd * w0.z + b0.z;
    o8[3] = (v[3] - mu) * rstd * w0.w + b0.w;
    o8[4] = (v[4] - mu) * rstd * w1.x + b1.x;
    o8[5] = (v[5] - mu) * rstd * w1.y + b1.y;
    o8[6] = (v[6] - mu) * rstd * w1.z + b1.z;
    o8[7] = (v[7] - mu) * rstd * w1.w + b1.w;
    uint4 o4;
    o4.x = (uint)f2b(o8[0]) | ((uint)f2b(o8[1]) << 16);
    o4.y = (uint)f2b(o8[2]) | ((uint)f2b(o8[3]) << 16);
    o4.z = (uint)f2b(o8[4]) | ((uint)f2b(o8[5]) << 16);
    o4.w = (uint)f2b(o8[6]) | ((uint)f2b(o8[7]) << 16);
    ((uint4*)(out + (size_t)row * 512))[lane] = o4;
}

// ---------- prep: cvt 4 weights + LN1 ----------
__device__ __forceinline__ void prep_body(
    int bi, const float* __restrict__ qkvw, u16* __restrict__ wq,
    const float* __restrict__ projw, u16* __restrict__ wp,
    const float* __restrict__ fc1w, u16* __restrict__ w1,
    const float* __restrict__ fc2w, u16* __restrict__ w2,
    const float* __restrict__ x, const float* __restrict__ n1w,
    const float* __restrict__ n1b, u16* __restrict__ hb) {
    if (bi < 3072) {
        const float* src;
        u16* dst;
        int i0;
        if (bi < 768)       { src = qkvw; dst = wq; i0 = bi; }
        else if (bi < 1024) { src = projw; dst = wp; i0 = bi - 768; }
        else if (bi < 2048) { src = fc1w; dst = w1; i0 = bi - 1024; }
        else                { src = fc2w; dst = w2; i0 = bi - 2048; }
        int i = i0 * 256 + threadIdx.x;
        float4 v = ((const float4*)src)[i];
        uint2 o;
        o.x = (uint)f2b(v.x) | ((uint)f2b(v.y) << 16);
        o.y = (uint)f2b(v.z) | ((uint)f2b(v.w) << 16);
        ((uint2*)dst)[i] = o;
    } else {
        int row = (bi - 3072) * 4 + (threadIdx.x >> 6);
        ln_row_wave_f32(x, n1w, n1b, hb, row);
    }
}

// ---------- GEMM A: 16x16x32 MFMA, MI=NI=4 frag reuse, dbuf, 128x128 BK=64 ----
// EPI: 0 bias->bf16 | 2 bias+GELU->bf16
template <int EPI>
__device__ __forceinline__ void gemm16_body(SMem& sm, int bx, int by,
                                            const u16* __restrict__ A,
                                            const u16* __restrict__ W,
                                            const float* __restrict__ bias,
                                            u16* __restrict__ outB,
                                            int M, int Nn, int K) {
    constexpr int BM = 128, BN = 128, BK = 64;
    int tid = threadIdx.x;
    int wid = tid >> 6, lane = tid & 63;
    int wm = wid >> 1, wn = wid & 1;
    int m_blk = bx * BM;
    int n_blk = by * BN;
    int lr = lane & 15;
    int lkc = lane >> 4;

    floatx4 acc[4][4];
    #pragma unroll
    for (int i = 0; i < 4; i++)
        #pragma unroll
        for (int j = 0; j < 4; j++) acc[i][j] = (floatx4){0.f, 0.f, 0.f, 0.f};

    const u16* Ag = A + (size_t)m_blk * K;
    const u16* Wg = W + (size_t)n_blk * K;

    int srow = tid >> 3;
    int skc = (tid & 7) ^ (srow & 7);

    auto stage = [&](int k0, int buf) {
        #pragma unroll
        for (int p = 0; p < 4; p++)
            gl_lds16(Ag + (size_t)(p * 32 + srow) * K + k0 + skc * 8,
                     sm.g16.a[buf] + (p * 256 + tid) * 8);
        #pragma unroll
        for (int p = 0; p < 4; p++)
            gl_lds16(Wg + (size_t)(p * 32 + srow) * K + k0 + skc * 8,
                     sm.g16.b[buf] + (p * 256 + tid) * 8);
    };

    stage(0, 0);
    int nit = K >> 6;
    for (int it = 0; it < nit; it++) {
        __syncthreads();
        if (it + 1 < nit) stage((it + 1) << 6, (it + 1) & 1);
        int cb = it & 1;
        #pragma unroll
        for (int s = 0; s < 2; s++) {
            int kc = s * 4 + lkc;
            shortx8 af[4], bf[4];
            #pragma unroll
            for (int i = 0; i < 4; i++) {
                int row = wm * 64 + i * 16 + lr;
                af[i] = *(const shortx8*)(sm.g16.a[cb] + (row * 8 + (kc ^ (row & 7))) * 8);
            }
            #pragma unroll
            for (int j = 0; j < 4; j++) {
                int row = wn * 64 + j * 16 + lr;
                bf[j] = *(const shortx8*)(sm.g16.b[cb] + (row * 8 + (kc ^ (row & 7))) * 8);
            }
            #pragma unroll
            for (int i = 0; i < 4; i++)
                #pragma unroll
                for (int j = 0; j < 4; j++)
                    acc[i][j] = __builtin_amdgcn_mfma_f32_16x16x32_bf16(
                        af[i], bf[j], acc[i][j], 0, 0, 0);
        }
    }

    int col_l = lane & 15;
    int row_base = (lane >> 4) * 4;
    #pragma unroll
    for (int nj = 0; nj < 4; nj++) {
        int col = n_blk + wn * 64 + nj * 16 + col_l;
        float bv = bias[col];
        #pragma unroll
        for (int mi = 0; mi < 4; mi++) {
            #pragma unroll
            for (int r = 0; r < 4; r++) {
                int row = m_blk + wm * 64 + mi * 16 + row_base + r;
                size_t off = (size_t)row * Nn + col;
                float v = acc[mi][nj][r] + bv;
                outB[off] = f2b(EPI == 2 ? gelu_f(v) : v);
            }
        }
    }
}

// ---------- GEMM B: 32x32x16, 64x64 block, BK=128, dbuf (N=512 GEMMs) ----------
// EPI: 1 bias+residF32->bf16 | 3 bias+residB16->fp32
template <int EPI>
__device__ __forceinline__ void gemm32_body(SMem& sm, int bx, int by,
                                            const u16* __restrict__ A,
                                            const u16* __restrict__ W,
                                            const float* __restrict__ bias,
                                            const float* __restrict__ residF,
                                            const u16* __restrict__ residB,
                                            float* __restrict__ outF,
                                            u16* __restrict__ outB,
                                            int M, int Nn, int K) {
    constexpr int BM = 64, BN = 64, BK = 128;
    constexpr int CPR = BK / 8, KMSK = CPR - 1;
    int tid = threadIdx.x;
    int wid = tid >> 6, lane = tid & 63;
    int wm = wid >> 1, wn = wid & 1;
    int m_blk = bx * BM;
    int n_blk = by * BN;
    int lr = lane & 31;
    int lk = lane >> 5;

    floatx16 acc;
    #pragma unroll
    for (int r = 0; r < 16; r++) acc[r] = 0.f;

    const u16* Ag = A + (size_t)m_blk * K;
    const u16* Wg = W + (size_t)n_blk * K;

    int srow = tid / CPR;
    int skc = (tid & KMSK) ^ (srow & KMSK);

    auto stage = [&](int k0, int buf) {
        #pragma unroll
        for (int p = 0; p < 4; p++)
            gl_lds16(Ag + (size_t)(p * 16 + srow) * K + k0 + skc * 8,
                     sm.g32.a[buf] + (p * 256 + tid) * 8);
        #pragma unroll
        for (int p = 0; p < 4; p++)
            gl_lds16(Wg + (size_t)(p * 16 + srow) * K + k0 + skc * 8,
                     sm.g32.b[buf] + (p * 256 + tid) * 8);
    };

    stage(0, 0);
    int nit = K / BK;
    for (int it = 0; it < nit; it++) {
        __syncthreads();
        if (it + 1 < nit) stage((it + 1) * BK, (it + 1) & 1);
        int cb = it & 1;
        #pragma unroll
        for (int s = 0; s < BK / 16; s++) {
            int kc = s * 2 + lk;
            int arow = wm * 32 + lr;
            int brow = wn * 32 + lr;
            shortx8 af = *(const shortx8*)(sm.g32.a[cb] + (arow * CPR + (kc ^ (arow & KMSK))) * 8);
            shortx8 bf = *(const shortx8*)(sm.g32.b[cb] + (brow * CPR + (kc ^ (brow & KMSK))) * 8);
            acc = __builtin_amdgcn_mfma_f32_32x32x16_bf16(af, bf, acc, 0, 0, 0);
        }
    }

    int col_l = lane & 31;
    int row_q = 4 * (lane >> 5);
    int col = n_blk + wn * 32 + col_l;
    float bv = bias[col];
    #pragma unroll
    for (int r = 0; r < 16; r++) {
        int row = m_blk + wm * 32 + (r & 3) + 8 * (r >> 2) + row_q;
        size_t off = (size_t)row * Nn + col;
        float v = acc[r] + bv;
        if (EPI == 1) outB[off] = f2b(v + residF[off]);
        else          outF[off] = v + b2f(residB[off]);
    }
}

// ---------- windowed attention, MFMA flash-style ----------
__device__ __forceinline__ void attn_body(SMem& sm, int bxx,
                                          const u16* __restrict__ qkv,
                                          const float* __restrict__ rel_bias,
                                          u16* __restrict__ out) {
    int n = bxx >> 8;
    int h = (bxx >> 5) & 7;
    int t0 = (bxx & 31) << 6;
    int tid = threadIdx.x, wid = tid >> 6, lane = tid & 63;
    int col = lane & 15, rq = lane >> 4;

    const u16* qrow = qkv + (size_t)(n * 2048 + t0 + wid * 16 + col) * 1536 + h * 64 + rq * 8;
    shortx8 qf0 = *(const shortx8*)qrow;
    shortx8 qf1 = *(const shortx8*)(qrow + 32);

    if (tid < 63) sm.at.bias[tid] = rel_bias[h * 63 + tid];
    if (tid == 63) sm.at.bias[63] = 0.f;

    const uint* qkv_u = (const uint*)qkv;
    // K tile: vectorized uint2 loads (8B/lane), 8 iters
    for (int idx = tid; idx < 128 * 16; idx += 256) {
        int row = idx >> 4, j2 = idx & 15;
        int pos = t0 - 31 + row;
        uint2 kv; kv.x = 0u; kv.y = 0u;
        if (pos >= 0 && pos < 2048)
            kv = *(const uint2*)(qkv_u + (size_t)(n * 2048 + pos) * 768 + 256 + h * 32 + j2 * 2);
        *(uint2*)&sm.at.k[row][j2 * 4] = kv;
    }
    // V transpose: row-pairs, packed b32 LDS writes (halves write insts)
    for (int idx = tid; idx < 72 * 32; idx += 256) {
        int rp = idx >> 5, j = idx & 31;
        int r0 = rp * 2;
        int p0 = t0 - 31 + r0, p1 = p0 + 1;
        uint a = 0u, b = 0u;
        if (p0 >= 0 && p0 < 2048)
            a = qkv_u[(size_t)(n * 2048 + p0) * 768 + 512 + h * 32 + j];
        if (p1 >= 0 && p1 < 2048)
            b = qkv_u[(size_t)(n * 2048 + p1) * 768 + 512 + h * 32 + j];
        *(uint*)&sm.at.v[2 * j][r0]     = (a & 0xffffu) | (b << 16);
        *(uint*)&sm.at.v[2 * j + 1][r0] = (a >> 16) | (b & 0xffff0000u);
    }
    __syncthreads();

    floatx4 S[5];
    #pragma unroll
    for (int nt = 0; nt < 5; nt++) S[nt] = (floatx4){0.f, 0.f, 0.f, 0.f};
    #pragma unroll
    for (int nt = 0; nt < 5; nt++) {
        const u16* kb = &sm.at.k[wid * 16 + nt * 16 + col][rq * 8];
        shortx8 b0 = *(const shortx8*)kb;
        shortx8 b1 = *(const shortx8*)(kb + 32);
        S[nt] = __builtin_amdgcn_mfma_f32_16x16x32_bf16(qf0, b0, S[nt], 0, 0, 0);
        S[nt] = __builtin_amdgcn_mfma_f32_16x16x32_bf16(qf1, b1, S[nt], 0, 0, 0);
    }

    #pragma unroll
    for (int r = 0; r < 4; r++) {
        int t_row = rq * 4 + r;
        float sc[5];
        float mx = -1e30f;
        #pragma unroll
        for (int nt = 0; nt < 5; nt++) {
            int w = nt * 16 + col - t_row;
            int pos_abs = t0 - 31 + wid * 16 + nt * 16 + col;
            float v;
            if (w < 0 || w > 62) {
                v = -1e30f;
            } else {
                v = S[nt][r] * 0.125f + sm.at.bias[w];
                if (pos_abs < 0 || pos_abs >= 2048) v -= 100.f;
            }
            sc[nt] = v;
            mx = fmaxf(mx, v);
        }
        #pragma unroll
        for (int o = 1; o < 16; o <<= 1) mx = fmaxf(mx, __shfl_xor(mx, o, 64));
        float l = 0.f;
        #pragma unroll
        for (int nt = 0; nt < 5; nt++) {
            sc[nt] = __expf(sc[nt] - mx);
            l += sc[nt];
        }
        #pragma unroll
        for (int o = 1; o < 16; o <<= 1) l += __shfl_xor(l, o, 64);
        float inv = 1.0f / l;
        #pragma unroll
        for (int nt = 0; nt < 5; nt++)
            sm.at.p[wid][t_row][nt * 16 + col] = f2b(sc[nt] * inv);
        sm.at.p[wid][t_row][80 + col] = 0;
    }
    __syncthreads();

    floatx4 O[4];
    #pragma unroll
    for (int dt = 0; dt < 4; dt++) O[dt] = (floatx4){0.f, 0.f, 0.f, 0.f};
    const u16* pr = &sm.at.p[wid][col][rq * 8];
    shortx8 a0 = *(const shortx8*)pr;
    shortx8 a1 = *(const shortx8*)(pr + 32);
    shortx8 a2 = *(const shortx8*)(pr + 64);
    #pragma unroll
    for (int dt = 0; dt < 4; dt++) {
        const u16* vb = &sm.at.v[dt * 16 + col][wid * 16 + rq * 8];
        shortx8 b0 = *(const shortx8*)vb;
        shortx8 b1 = *(const shortx8*)(vb + 32);
        shortx8 b2 = *(const shortx8*)(vb + 64);
        O[dt] = __builtin_amdgcn_mfma_f32_16x16x32_bf16(a0, b0, O[dt], 0, 0, 0);
        O[dt] = __builtin_amdgcn_mfma_f32_16x16x32_bf16(a1, b1, O[dt], 0, 0, 0);
        O[dt] = __builtin_amdgcn_mfma_f32_16x16x32_bf16(a2, b2, O[dt], 0, 0, 0);
    }

    #pragma unroll
    for (int dt = 0; dt < 4; dt++) {
        #pragma unroll
        for (int r = 0; r < 4; r++) {
            int t_row = rq * 4 + r;
            out[(size_t)(n * 2048 + t0 + wid * 16 + t_row) * 512 + h * 64 + dt * 16 + col] =
                f2b(O[dt][r]);
        }
    }
}

// ---------- fused persistent kernel: whole layer, 7 phases, 6 grid barriers ----
__global__ __launch_bounds__(256, 2) void fused_layer(
    const float* __restrict__ x, const float* __restrict__ n1w,
    const float* __restrict__ n1b, const float* __restrict__ qkvw,
    const float* __restrict__ qkvbv, const float* __restrict__ relb,
    const float* __restrict__ projw, const float* __restrict__ projb,
    const float* __restrict__ n2w, const float* __restrict__ n2b,
    const float* __restrict__ fc1w, const float* __restrict__ fc1b,
    const float* __restrict__ fc2w, const float* __restrict__ fc2b,
    float* __restrict__ out,
    u16* __restrict__ wq, u16* __restrict__ wp, u16* __restrict__ w1,
    u16* __restrict__ w2, u16* __restrict__ hb, u16* __restrict__ qkvb,
    u16* __restrict__ attb, u16* __restrict__ x2b, u16* __restrict__ mb,
    unsigned* __restrict__ ctrs) {
    __shared__ SMem sm;
    int b = blockIdx.x;

    // phase 0: weight cvt + LN1 (4096 vblocks)
    for (int vb = b; vb < 4096; vb += 512)
        prep_body(vb, qkvw, wq, projw, wp, fc1w, w1, fc2w, w2, x, n1w, n1b, hb);
    gbar(&ctrs[0], 512);

    // phase 1: qkv = hb @ wq^T + b   (4096x1536, K=512) — 384 vblocks
    if (b < 384)
        gemm16_body<0>(sm, b & 31, b >> 5, hb, wq, qkvbv, qkvb, 4096, 1536, 512);
    gbar(&ctrs[1], 512);

    // phase 2: windowed attention — 512 vblocks
    attn_body(sm, b, qkvb, relb, attb);
    gbar(&ctrs[2], 512);

    // phase 3: x2 = x + attb @ wp^T + b  (4096x512, K=512) — 512 vblocks
    gemm32_body<1>(sm, b & 63, b >> 6, attb, wp, projb, x, nullptr,
                   nullptr, x2b, 4096, 512, 512);
    gbar(&ctrs[3], 512);

    // phase 4: LN2 (1024 vblocks x 4 rows)
    for (int vb = b; vb < 1024; vb += 512) {
        int row = vb * 4 + (threadIdx.x >> 6);
        ln_row_wave_b16(x2b, n2w, n2b, hb, row);
    }
    gbar(&ctrs[4], 512);

    // phase 5: mb = gelu(hb @ w1^T + b)  (4096x2048, K=512) — 512 vblocks
    gemm16_body<2>(sm, b & 31, b >> 5, hb, w1, fc1b, mb, 4096, 2048, 512);
    gbar(&ctrs[5], 512);

    // phase 6: out = x2 + mb @ w2^T + b  (4096x512, K=2048) — 512 vblocks
    gemm32_body<3>(sm, b & 63, b >> 6, mb, w2, fc2b, nullptr, x2b,
                   out, nullptr, 4096, 512, 2048);
}

// ---------- launcher ----------
extern "C" void kernel_launch(void* const* d_in, const int* in_sizes, int n_in,
                              void* d_out, int out_size, void* d_ws, size_t ws_size,
                              hipStream_t stream) {
    const float* x     = (const float*)d_in[0];
    const float* n1w   = (const float*)d_in[1];
    const float* n1b   = (const float*)d_in[2];
    const float* qkvw  = (const float*)d_in[3];
    const float* qkvbv = (const float*)d_in[4];
    const float* relb  = (const float*)d_in[5];
    const float* projw = (const float*)d_in[6];
    const float* projb = (const float*)d_in[7];
    const float* n2w   = (const float*)d_in[8];
    const float* n2b   = (const float*)d_in[9];
    const float* fc1w  = (const float*)d_in[10];
    const float* fc1b  = (const float*)d_in[11];
    const float* fc2w  = (const float*)d_in[12];
    const float* fc2b  = (const float*)d_in[13];
    float* out = (float*)d_out;

    char* p = (char*)d_ws;
    u16* wq   = (u16*)p;  p += (size_t)786432 * 2;   // qkv_w bf16 (1536x512)
    u16* wp   = (u16*)p;  p += (size_t)262144 * 2;   // proj_w bf16 (512x512)
    u16* w1   = (u16*)p;  p += (size_t)1048576 * 2;  // fc1_w bf16 (2048x512)
    u16* w2   = (u16*)p;  p += (size_t)1048576 * 2;  // fc2_w bf16 (512x2048)
    u16* hb   = (u16*)p;  p += (size_t)2097152 * 2;  // h / h2 bf16 (4096x512)
    u16* qkvb = (u16*)p;  p += (size_t)6291456 * 2;  // qkv bf16 (4096x1536)
    u16* attb = (u16*)p;  p += (size_t)2097152 * 2;  // attn out bf16 (4096x512)
    u16* x2b  = (u16*)p;  p += (size_t)2097152 * 2;  // x + proj(attn), bf16
    u16* mb   = (u16*)p;  p += (size_t)8388608 * 2;  // gelu(fc1) bf16 (4096x2048)
    unsigned* ctrs = (unsigned*)p;                   // 6 barrier counters

    hipMemsetAsync(ctrs, 0, 64, stream);
    fused_layer<<<512, 256, 0, stream>>>(x, n1w, n1b, qkvw, qkvbv, relb, projw,
                                         projb, n2w, n2b, fc1w, fc1b, fc2w, fc2b,
                                         out, wq, wp, w1, w2, hb, qkvb, attb,
                                         x2b, mb, ctrs);
}

// Round 2
// 410.445 us; speedup vs baseline: 1.6085x; 1.6085x over previous
//
#include <hip/hip_runtime.h>

typedef unsigned short u16;
typedef unsigned int uint;
typedef __attribute__((ext_vector_type(4))) float floatx4;
typedef __attribute__((ext_vector_type(16))) float floatx16;
typedef __attribute__((ext_vector_type(8))) short shortx8;

// ---------- helpers ----------
__device__ __forceinline__ u16 f2b(float f) {
    unsigned int u = __float_as_uint(f);
    unsigned int r = (u + 0x7fffu + ((u >> 16) & 1u)) >> 16;
    return (u16)r;
}
__device__ __forceinline__ float b2f(u16 u) {
    return __uint_as_float(((unsigned int)u) << 16);
}
__device__ __forceinline__ void gl_lds16(const u16* g, u16* l) {
    __builtin_amdgcn_global_load_lds(
        (const __attribute__((address_space(1))) void*)g,
        (__attribute__((address_space(3))) void*)l, 16, 0, 0);
}
__device__ __forceinline__ float gelu_f(float v) {
    float e = __expf(1.59576912f * v * (1.0f + 0.044715f * v * v));
    return v * e / (e + 1.0f);
}

// ---------- shared-memory union (64 KiB): 2 blocks/CU guaranteed ----------
struct SG16 { u16 a[2][128 * 64]; u16 b[2][128 * 64]; };   // 64 KiB
struct SG32 { u16 a[2][64 * 128]; u16 b[2][64 * 128]; };   // 64 KiB
struct SAttn {
    u16 k[128][72];
    u16 v[64][152];
    u16 p[4][16][104];
    float bias[64];
};                                                          // ~50 KiB
union SMem { SG16 g16; SG32 g32; SAttn at; };
static_assert(sizeof(SMem) == 65536, "smem union must be 64KiB");

// ---------- device-scope grid barrier, minimal fencing ----------
// R1 lesson: an AGENT-scope ACQUIRE poll emits an L1+L2 invalidate EVERY
// iteration -> 64 spinners/XCD continuously nuke L2 while stragglers still
// compute (565us, all pipes idle). Correct schedule: one release fence
// (waitcnt+wbL2, no inv) at arrival, RELAXED add + RELAXED polls (scope bits
// alone make the atomic read the coherent copy), ONE acquire fence (inv) at
// exit. This matches what every kernel boundary already does implicitly.
__device__ __forceinline__ void gbar(unsigned* c, unsigned tgt) {
    __syncthreads();
    if (threadIdx.x == 0) {
        __builtin_amdgcn_fence(__ATOMIC_RELEASE, "agent");   // wb dirty L2, no inv
        __hip_atomic_fetch_add(c, 1u, __ATOMIC_RELAXED, __HIP_MEMORY_SCOPE_AGENT);
        while (__hip_atomic_load(c, __ATOMIC_RELAXED, __HIP_MEMORY_SCOPE_AGENT) < tgt)
            __builtin_amdgcn_s_sleep(8);                     // ~512cy backoff
        __builtin_amdgcn_fence(__ATOMIC_ACQUIRE, "agent");   // single inv at exit
    }
    __syncthreads();
}

// ---------- wave-per-row LN (C=512): 8 elems/lane, shuffle-only ----------
__device__ __forceinline__ void ln_row_wave_f32(const float* __restrict__ x,
                                                const float* __restrict__ w,
                                                const float* __restrict__ b,
                                                u16* __restrict__ out, int row) {
    int lane = threadIdx.x & 63;
    const float4* xr = (const float4*)(x + (size_t)row * 512);
    float4 v0 = xr[lane * 2], v1 = xr[lane * 2 + 1];
    float s = v0.x + v0.y + v0.z + v0.w + v1.x + v1.y + v1.z + v1.w;
    float s2 = v0.x * v0.x + v0.y * v0.y + v0.z * v0.z + v0.w * v0.w +
               v1.x * v1.x + v1.y * v1.y + v1.z * v1.z + v1.w * v1.w;
    #pragma unroll
    for (int o = 32; o > 0; o >>= 1) {
        s += __shfl_xor(s, o, 64);
        s2 += __shfl_xor(s2, o, 64);
    }
    float mu = s * (1.0f / 512.0f);
    float var = s2 * (1.0f / 512.0f) - mu * mu;
    float rstd = rsqrtf(var + 1e-5f);
    const float4* wr = (const float4*)w;
    const float4* br = (const float4*)b;
    float4 w0 = wr[lane * 2], w1 = wr[lane * 2 + 1];
    float4 b0 = br[lane * 2], b1 = br[lane * 2 + 1];
    uint4 o4;
    o4.x = (uint)f2b((v0.x - mu) * rstd * w0.x + b0.x) |
           ((uint)f2b((v0.y - mu) * rstd * w0.y + b0.y) << 16);
    o4.y = (uint)f2b((v0.z - mu) * rstd * w0.z + b0.z) |
           ((uint)f2b((v0.w - mu) * rstd * w0.w + b0.w) << 16);
    o4.z = (uint)f2b((v1.x - mu) * rstd * w1.x + b1.x) |
           ((uint)f2b((v1.y - mu) * rstd * w1.y + b1.y) << 16);
    o4.w = (uint)f2b((v1.z - mu) * rstd * w1.z + b1.z) |
           ((uint)f2b((v1.w - mu) * rstd * w1.w + b1.w) << 16);
    ((uint4*)(out + (size_t)row * 512))[lane] = o4;
}

__device__ __forceinline__ void ln_row_wave_b16(const u16* __restrict__ x,
                                                const float* __restrict__ w,
                                                const float* __restrict__ b,
                                                u16* __restrict__ out, int row) {
    int lane = threadIdx.x & 63;
    uint4 p = ((const uint4*)(x + (size_t)row * 512))[lane];
    float v[8];
    v[0] = b2f((u16)(p.x & 0xffffu)); v[1] = b2f((u16)(p.x >> 16));
    v[2] = b2f((u16)(p.y & 0xffffu)); v[3] = b2f((u16)(p.y >> 16));
    v[4] = b2f((u16)(p.z & 0xffffu)); v[5] = b2f((u16)(p.z >> 16));
    v[6] = b2f((u16)(p.w & 0xffffu)); v[7] = b2f((u16)(p.w >> 16));
    float s = 0.f, s2 = 0.f;
    #pragma unroll
    for (int i = 0; i < 8; i++) { s += v[i]; s2 += v[i] * v[i]; }
    #pragma unroll
    for (int o = 32; o > 0; o >>= 1) {
        s += __shfl_xor(s, o, 64);
        s2 += __shfl_xor(s2, o, 64);
    }
    float mu = s * (1.0f / 512.0f);
    float var = s2 * (1.0f / 512.0f) - mu * mu;
    float rstd = rsqrtf(var + 1e-5f);
    const float4* wr = (const float4*)w;
    const float4* br = (const float4*)b;
    float4 w0 = wr[lane * 2], w1 = wr[lane * 2 + 1];
    float4 b0 = br[lane * 2], b1 = br[lane * 2 + 1];
    float o8[8];
    o8[0] = (v[0] - mu) * rstd * w0.x + b0.x;
    o8[1] = (v[1] - mu) * rstd * w0.y + b0.y;
    o8[2] = (v[2] - mu) * rstd * w0.z + b0.z;
    o8[3] = (v[3] - mu) * rstd * w0.w + b0.w;
    o8[4] = (v[4] - mu) * rstd * w1.x + b1.x;
    o8[5] = (v[5] - mu) * rstd * w1.y + b1.y;
    o8[6] = (v[6] - mu) * rstd * w1.z + b1.z;
    o8[7] = (v[7] - mu) * rstd * w1.w + b1.w;
    uint4 o4;
    o4.x = (uint)f2b(o8[0]) | ((uint)f2b(o8[1]) << 16);
    o4.y = (uint)f2b(o8[2]) | ((uint)f2b(o8[3]) << 16);
    o4.z = (uint)f2b(o8[4]) | ((uint)f2b(o8[5]) << 16);
    o4.w = (uint)f2b(o8[6]) | ((uint)f2b(o8[7]) << 16);
    ((uint4*)(out + (size_t)row * 512))[lane] = o4;
}

// ---------- prep: cvt 4 weights + LN1 ----------
__device__ __forceinline__ void prep_body(
    int bi, const float* __restrict__ qkvw, u16* __restrict__ wq,
    const float* __restrict__ projw, u16* __restrict__ wp,
    const float* __restrict__ fc1w, u16* __restrict__ w1,
    const float* __restrict__ fc2w, u16* __restrict__ w2,
    const float* __restrict__ x, const float* __restrict__ n1w,
    const float* __restrict__ n1b, u16* __restrict__ hb) {
    if (bi < 3072) {
        const float* src;
        u16* dst;
        int i0;
        if (bi < 768)       { src = qkvw; dst = wq; i0 = bi; }
        else if (bi < 1024) { src = projw; dst = wp; i0 = bi - 768; }
        else if (bi < 2048) { src = fc1w; dst = w1; i0 = bi - 1024; }
        else                { src = fc2w; dst = w2; i0 = bi - 2048; }
        int i = i0 * 256 + threadIdx.x;
        float4 v = ((const float4*)src)[i];
        uint2 o;
        o.x = (uint)f2b(v.x) | ((uint)f2b(v.y) << 16);
        o.y = (uint)f2b(v.z) | ((uint)f2b(v.w) << 16);
        ((uint2*)dst)[i] = o;
    } else {
        int row = (bi - 3072) * 4 + (threadIdx.x >> 6);
        ln_row_wave_f32(x, n1w, n1b, hb, row);
    }
}

// ---------- GEMM A: 16x16x32 MFMA, MI=NI=4 frag reuse, dbuf, 128x128 BK=64 ----
// EPI: 0 bias->bf16 | 2 bias+GELU->bf16
template <int EPI>
__device__ __forceinline__ void gemm16_body(SMem& sm, int bx, int by,
                                            const u16* __restrict__ A,
                                            const u16* __restrict__ W,
                                            const float* __restrict__ bias,
                                            u16* __restrict__ outB,
                                            int M, int Nn, int K) {
    constexpr int BM = 128, BN = 128, BK = 64;
    int tid = threadIdx.x;
    int wid = tid >> 6, lane = tid & 63;
    int wm = wid >> 1, wn = wid & 1;
    int m_blk = bx * BM;
    int n_blk = by * BN;
    int lr = lane & 15;
    int lkc = lane >> 4;

    floatx4 acc[4][4];
    #pragma unroll
    for (int i = 0; i < 4; i++)
        #pragma unroll
        for (int j = 0; j < 4; j++) acc[i][j] = (floatx4){0.f, 0.f, 0.f, 0.f};

    const u16* Ag = A + (size_t)m_blk * K;
    const u16* Wg = W + (size_t)n_blk * K;

    int srow = tid >> 3;
    int skc = (tid & 7) ^ (srow & 7);

    auto stage = [&](int k0, int buf) {
        #pragma unroll
        for (int p = 0; p < 4; p++)
            gl_lds16(Ag + (size_t)(p * 32 + srow) * K + k0 + skc * 8,
                     sm.g16.a[buf] + (p * 256 + tid) * 8);
        #pragma unroll
        for (int p = 0; p < 4; p++)
            gl_lds16(Wg + (size_t)(p * 32 + srow) * K + k0 + skc * 8,
                     sm.g16.b[buf] + (p * 256 + tid) * 8);
    };

    stage(0, 0);
    int nit = K >> 6;
    for (int it = 0; it < nit; it++) {
        __syncthreads();
        if (it + 1 < nit) stage((it + 1) << 6, (it + 1) & 1);
        int cb = it & 1;
        #pragma unroll
        for (int s = 0; s < 2; s++) {
            int kc = s * 4 + lkc;
            shortx8 af[4], bf[4];
            #pragma unroll
            for (int i = 0; i < 4; i++) {
                int row = wm * 64 + i * 16 + lr;
                af[i] = *(const shortx8*)(sm.g16.a[cb] + (row * 8 + (kc ^ (row & 7))) * 8);
            }
            #pragma unroll
            for (int j = 0; j < 4; j++) {
                int row = wn * 64 + j * 16 + lr;
                bf[j] = *(const shortx8*)(sm.g16.b[cb] + (row * 8 + (kc ^ (row & 7))) * 8);
            }
            #pragma unroll
            for (int i = 0; i < 4; i++)
                #pragma unroll
                for (int j = 0; j < 4; j++)
                    acc[i][j] = __builtin_amdgcn_mfma_f32_16x16x32_bf16(
                        af[i], bf[j], acc[i][j], 0, 0, 0);
        }
    }

    int col_l = lane & 15;
    int row_base = (lane >> 4) * 4;
    #pragma unroll
    for (int nj = 0; nj < 4; nj++) {
        int col = n_blk + wn * 64 + nj * 16 + col_l;
        float bv = bias[col];
        #pragma unroll
        for (int mi = 0; mi < 4; mi++) {
            #pragma unroll
            for (int r = 0; r < 4; r++) {
                int row = m_blk + wm * 64 + mi * 16 + row_base + r;
                size_t off = (size_t)row * Nn + col;
                float v = acc[mi][nj][r] + bv;
                outB[off] = f2b(EPI == 2 ? gelu_f(v) : v);
            }
        }
    }
}

// ---------- GEMM B: 32x32x16, 64x64 block, BK=128, dbuf (N=512 GEMMs) ----------
// EPI: 1 bias+residF32->bf16 | 3 bias+residB16->fp32
template <int EPI>
__device__ __forceinline__ void gemm32_body(SMem& sm, int bx, int by,
                                            const u16* __restrict__ A,
                                            const u16* __restrict__ W,
                                            const float* __restrict__ bias,
                                            const float* __restrict__ residF,
                                            const u16* __restrict__ residB,
                                            float* __restrict__ outF,
                                            u16* __restrict__ outB,
                                            int M, int Nn, int K) {
    constexpr int BM = 64, BN = 64, BK = 128;
    constexpr int CPR = BK / 8, KMSK = CPR - 1;
    int tid = threadIdx.x;
    int wid = tid >> 6, lane = tid & 63;
    int wm = wid >> 1, wn = wid & 1;
    int m_blk = bx * BM;
    int n_blk = by * BN;
    int lr = lane & 31;
    int lk = lane >> 5;

    floatx16 acc;
    #pragma unroll
    for (int r = 0; r < 16; r++) acc[r] = 0.f;

    const u16* Ag = A + (size_t)m_blk * K;
    const u16* Wg = W + (size_t)n_blk * K;

    int srow = tid / CPR;
    int skc = (tid & KMSK) ^ (srow & KMSK);

    auto stage = [&](int k0, int buf) {
        #pragma unroll
        for (int p = 0; p < 4; p++)
            gl_lds16(Ag + (size_t)(p * 16 + srow) * K + k0 + skc * 8,
                     sm.g32.a[buf] + (p * 256 + tid) * 8);
        #pragma unroll
        for (int p = 0; p < 4; p++)
            gl_lds16(Wg + (size_t)(p * 16 + srow) * K + k0 + skc * 8,
                     sm.g32.b[buf] + (p * 256 + tid) * 8);
    };

    stage(0, 0);
    int nit = K / BK;
    for (int it = 0; it < nit; it++) {
        __syncthreads();
        if (it + 1 < nit) stage((it + 1) * BK, (it + 1) & 1);
        int cb = it & 1;
        #pragma unroll
        for (int s = 0; s < BK / 16; s++) {
            int kc = s * 2 + lk;
            int arow = wm * 32 + lr;
            int brow = wn * 32 + lr;
            shortx8 af = *(const shortx8*)(sm.g32.a[cb] + (arow * CPR + (kc ^ (arow & KMSK))) * 8);
            shortx8 bf = *(const shortx8*)(sm.g32.b[cb] + (brow * CPR + (kc ^ (brow & KMSK))) * 8);
            acc = __builtin_amdgcn_mfma_f32_32x32x16_bf16(af, bf, acc, 0, 0, 0);
        }
    }

    int col_l = lane & 31;
    int row_q = 4 * (lane >> 5);
    int col = n_blk + wn * 32 + col_l;
    float bv = bias[col];
    #pragma unroll
    for (int r = 0; r < 16; r++) {
        int row = m_blk + wm * 32 + (r & 3) + 8 * (r >> 2) + row_q;
        size_t off = (size_t)row * Nn + col;
        float v = acc[r] + bv;
        if (EPI == 1) outB[off] = f2b(v + residF[off]);
        else          outF[off] = v + b2f(residB[off]);
    }
}

// ---------- windowed attention, MFMA flash-style ----------
__device__ __forceinline__ void attn_body(SMem& sm, int bxx,
                                          const u16* __restrict__ qkv,
                                          const float* __restrict__ rel_bias,
                                          u16* __restrict__ out) {
    int n = bxx >> 8;
    int h = (bxx >> 5) & 7;
    int t0 = (bxx & 31) << 6;
    int tid = threadIdx.x, wid = tid >> 6, lane = tid & 63;
    int col = lane & 15, rq = lane >> 4;

    const u16* qrow = qkv + (size_t)(n * 2048 + t0 + wid * 16 + col) * 1536 + h * 64 + rq * 8;
    shortx8 qf0 = *(const shortx8*)qrow;
    shortx8 qf1 = *(const shortx8*)(qrow + 32);

    if (tid < 63) sm.at.bias[tid] = rel_bias[h * 63 + tid];
    if (tid == 63) sm.at.bias[63] = 0.f;

    const uint* qkv_u = (const uint*)qkv;
    // K tile: vectorized uint2 loads (8B/lane), 8 iters
    for (int idx = tid; idx < 128 * 16; idx += 256) {
        int row = idx >> 4, j2 = idx & 15;
        int pos = t0 - 31 + row;
        uint2 kv; kv.x = 0u; kv.y = 0u;
        if (pos >= 0 && pos < 2048)
            kv = *(const uint2*)(qkv_u + (size_t)(n * 2048 + pos) * 768 + 256 + h * 32 + j2 * 2);
        *(uint2*)&sm.at.k[row][j2 * 4] = kv;
    }
    // V transpose: row-pairs, packed b32 LDS writes (halves write insts)
    for (int idx = tid; idx < 72 * 32; idx += 256) {
        int rp = idx >> 5, j = idx & 31;
        int r0 = rp * 2;
        int p0 = t0 - 31 + r0, p1 = p0 + 1;
        uint a = 0u, b = 0u;
        if (p0 >= 0 && p0 < 2048)
            a = qkv_u[(size_t)(n * 2048 + p0) * 768 + 512 + h * 32 + j];
        if (p1 >= 0 && p1 < 2048)
            b = qkv_u[(size_t)(n * 2048 + p1) * 768 + 512 + h * 32 + j];
        *(uint*)&sm.at.v[2 * j][r0]     = (a & 0xffffu) | (b << 16);
        *(uint*)&sm.at.v[2 * j + 1][r0] = (a >> 16) | (b & 0xffff0000u);
    }
    __syncthreads();

    floatx4 S[5];
    #pragma unroll
    for (int nt = 0; nt < 5; nt++) S[nt] = (floatx4){0.f, 0.f, 0.f, 0.f};
    #pragma unroll
    for (int nt = 0; nt < 5; nt++) {
        const u16* kb = &sm.at.k[wid * 16 + nt * 16 + col][rq * 8];
        shortx8 b0 = *(const shortx8*)kb;
        shortx8 b1 = *(const shortx8*)(kb + 32);
        S[nt] = __builtin_amdgcn_mfma_f32_16x16x32_bf16(qf0, b0, S[nt], 0, 0, 0);
        S[nt] = __builtin_amdgcn_mfma_f32_16x16x32_bf16(qf1, b1, S[nt], 0, 0, 0);
    }

    #pragma unroll
    for (int r = 0; r < 4; r++) {
        int t_row = rq * 4 + r;
        float sc[5];
        float mx = -1e30f;
        #pragma unroll
        for (int nt = 0; nt < 5; nt++) {
            int w = nt * 16 + col - t_row;
            int pos_abs = t0 - 31 + wid * 16 + nt * 16 + col;
            float v;
            if (w < 0 || w > 62) {
                v = -1e30f;
            } else {
                v = S[nt][r] * 0.125f + sm.at.bias[w];
                if (pos_abs < 0 || pos_abs >= 2048) v -= 100.f;
            }
            sc[nt] = v;
            mx = fmaxf(mx, v);
        }
        #pragma unroll
        for (int o = 1; o < 16; o <<= 1) mx = fmaxf(mx, __shfl_xor(mx, o, 64));
        float l = 0.f;
        #pragma unroll
        for (int nt = 0; nt < 5; nt++) {
            sc[nt] = __expf(sc[nt] - mx);
            l += sc[nt];
        }
        #pragma unroll
        for (int o = 1; o < 16; o <<= 1) l += __shfl_xor(l, o, 64);
        float inv = 1.0f / l;
        #pragma unroll
        for (int nt = 0; nt < 5; nt++)
            sm.at.p[wid][t_row][nt * 16 + col] = f2b(sc[nt] * inv);
        sm.at.p[wid][t_row][80 + col] = 0;
    }
    __syncthreads();

    floatx4 O[4];
    #pragma unroll
    for (int dt = 0; dt < 4; dt++) O[dt] = (floatx4){0.f, 0.f, 0.f, 0.f};
    const u16* pr = &sm.at.p[wid][col][rq * 8];
    shortx8 a0 = *(const shortx8*)pr;
    shortx8 a1 = *(const shortx8*)(pr + 32);
    shortx8 a2 = *(const shortx8*)(pr + 64);
    #pragma unroll
    for (int dt = 0; dt < 4; dt++) {
        const u16* vb = &sm.at.v[dt * 16 + col][wid * 16 + rq * 8];
        shortx8 b0 = *(const shortx8*)vb;
        shortx8 b1 = *(const shortx8*)(vb + 32);
        shortx8 b2 = *(const shortx8*)(vb + 64);
        O[dt] = __builtin_amdgcn_mfma_f32_16x16x32_bf16(a0, b0, O[dt], 0, 0, 0);
        O[dt] = __builtin_amdgcn_mfma_f32_16x16x32_bf16(a1, b1, O[dt], 0, 0, 0);
        O[dt] = __builtin_amdgcn_mfma_f32_16x16x32_bf16(a2, b2, O[dt], 0, 0, 0);
    }

    #pragma unroll
    for (int dt = 0; dt < 4; dt++) {
        #pragma unroll
        for (int r = 0; r < 4; r++) {
            int t_row = rq * 4 + r;
            out[(size_t)(n * 2048 + t0 + wid * 16 + t_row) * 512 + h * 64 + dt * 16 + col] =
                f2b(O[dt][r]);
        }
    }
}

// ---------- fused persistent kernel: whole layer, 7 phases, 6 grid barriers ----
__global__ __launch_bounds__(256, 2) void fused_layer(
    const float* __restrict__ x, const float* __restrict__ n1w,
    const float* __restrict__ n1b, const float* __restrict__ qkvw,
    const float* __restrict__ qkvbv, const float* __restrict__ relb,
    const float* __restrict__ projw, const float* __restrict__ projb,
    const float* __restrict__ n2w, const float* __restrict__ n2b,
    const float* __restrict__ fc1w, const float* __restrict__ fc1b,
    const float* __restrict__ fc2w, const float* __restrict__ fc2b,
    float* __restrict__ out,
    u16* __restrict__ wq, u16* __restrict__ wp, u16* __restrict__ w1,
    u16* __restrict__ w2, u16* __restrict__ hb, u16* __restrict__ qkvb,
    u16* __restrict__ attb, u16* __restrict__ x2b, u16* __restrict__ mb,
    unsigned* __restrict__ ctrs) {
    __shared__ SMem sm;
    int b = blockIdx.x;

    // phase 0: weight cvt + LN1 (4096 vblocks)
    for (int vb = b; vb < 4096; vb += 512)
        prep_body(vb, qkvw, wq, projw, wp, fc1w, w1, fc2w, w2, x, n1w, n1b, hb);
    gbar(&ctrs[0], 512);

    // phase 1: qkv = hb @ wq^T + b   (4096x1536, K=512) — 384 vblocks
    if (b < 384)
        gemm16_body<0>(sm, b & 31, b >> 5, hb, wq, qkvbv, qkvb, 4096, 1536, 512);
    gbar(&ctrs[1], 512);

    // phase 2: windowed attention — 512 vblocks
    attn_body(sm, b, qkvb, relb, attb);
    gbar(&ctrs[2], 512);

    // phase 3: x2 = x + attb @ wp^T + b  (4096x512, K=512) — 512 vblocks
    gemm32_body<1>(sm, b & 63, b >> 6, attb, wp, projb, x, nullptr,
                   nullptr, x2b, 4096, 512, 512);
    gbar(&ctrs[3], 512);

    // phase 4: LN2 (1024 vblocks x 4 rows)
    for (int vb = b; vb < 1024; vb += 512) {
        int row = vb * 4 + (threadIdx.x >> 6);
        ln_row_wave_b16(x2b, n2w, n2b, hb, row);
    }
    gbar(&ctrs[4], 512);

    // phase 5: mb = gelu(hb @ w1^T + b)  (4096x2048, K=512) — 512 vblocks
    gemm16_body<2>(sm, b & 31, b >> 5, hb, w1, fc1b, mb, 4096, 2048, 512);
    gbar(&ctrs[5], 512);

    // phase 6: out = x2 + mb @ w2^T + b  (4096x512, K=2048) — 512 vblocks
    gemm32_body<3>(sm, b & 63, b >> 6, mb, w2, fc2b, nullptr, x2b,
                   out, nullptr, 4096, 512, 2048);
}

// ---------- launcher ----------
extern "C" void kernel_launch(void* const* d_in, const int* in_sizes, int n_in,
                              void* d_out, int out_size, void* d_ws, size_t ws_size,
                              hipStream_t stream) {
    const float* x     = (const float*)d_in[0];
    const float* n1w   = (const float*)d_in[1];
    const float* n1b   = (const float*)d_in[2];
    const float* qkvw  = (const float*)d_in[3];
    const float* qkvbv = (const float*)d_in[4];
    const float* relb  = (const float*)d_in[5];
    const float* projw = (const float*)d_in[6];
    const float* projb = (const float*)d_in[7];
    const float* n2w   = (const float*)d_in[8];
    const float* n2b   = (const float*)d_in[9];
    const float* fc1w  = (const float*)d_in[10];
    const float* fc1b  = (const float*)d_in[11];
    const float* fc2w  = (const float*)d_in[12];
    const float* fc2b  = (const float*)d_in[13];
    float* out = (float*)d_out;

    char* p = (char*)d_ws;
    u16* wq   = (u16*)p;  p += (size_t)786432 * 2;   // qkv_w bf16 (1536x512)
    u16* wp   = (u16*)p;  p += (size_t)262144 * 2;   // proj_w bf16 (512x512)
    u16* w1   = (u16*)p;  p += (size_t)1048576 * 2;  // fc1_w bf16 (2048x512)
    u16* w2   = (u16*)p;  p += (size_t)1048576 * 2;  // fc2_w bf16 (512x2048)
    u16* hb   = (u16*)p;  p += (size_t)2097152 * 2;  // h / h2 bf16 (4096x512)
    u16* qkvb = (u16*)p;  p += (size_t)6291456 * 2;  // qkv bf16 (4096x1536)
    u16* attb = (u16*)p;  p += (size_t)2097152 * 2;  // attn out bf16 (4096x512)
    u16* x2b  = (u16*)p;  p += (size_t)2097152 * 2;  // x + proj(attn), bf16
    u16* mb   = (u16*)p;  p += (size_t)8388608 * 2;  // gelu(fc1) bf16 (4096x2048)
    unsigned* ctrs = (unsigned*)p;                   // 6 barrier counters

    hipMemsetAsync(ctrs, 0, 64, stream);
    fused_layer<<<512, 256, 0, stream>>>(x, n1w, n1b, qkvw, qkvbv, relb, projw,
                                         projb, n2w, n2b, fc1w, fc1b, fc2w, fc2b,
                                         out, wq, wp, w1, w2, hb, qkvb, attb,
                                         x2b, mb, ctrs);
}

// Round 3
// 289.280 us; speedup vs baseline: 2.2822x; 1.4189x over previous
//
#include <hip/hip_runtime.h>

typedef unsigned short u16;
typedef unsigned int uint;
typedef unsigned long long ull;
typedef __attribute__((ext_vector_type(4))) float floatx4;
typedef __attribute__((ext_vector_type(16))) float floatx16;
typedef __attribute__((ext_vector_type(8))) short shortx8;

#define ST_AGENT(p, v) __hip_atomic_store((p), (v), __ATOMIC_RELAXED, __HIP_MEMORY_SCOPE_AGENT)

// ---------- helpers ----------
__device__ __forceinline__ u16 f2b(float f) {
    unsigned int u = __float_as_uint(f);
    unsigned int r = (u + 0x7fffu + ((u >> 16) & 1u)) >> 16;
    return (u16)r;
}
__device__ __forceinline__ float b2f(u16 u) {
    return __uint_as_float(((unsigned int)u) << 16);
}
__device__ __forceinline__ void gl_lds16(const u16* g, u16* l) {
    __builtin_amdgcn_global_load_lds(
        (const __attribute__((address_space(1))) void*)g,
        (__attribute__((address_space(3))) void*)l, 16, 0, 0);
}
__device__ __forceinline__ float gelu_f(float v) {
    float e = __expf(1.59576912f * v * (1.0f + 0.044715f * v * v));
    return v * e / (e + 1.0f);
}
// pack own bf16 with lane^1 partner's into one uint (lo=even col, hi=odd col)
__device__ __forceinline__ uint pack_pair(uint u, int lane) {
    uint pt = (uint)__shfl_xor((int)u, 1, 64);
    return (lane & 1) ? (pt | (u << 16)) : (u | (pt << 16));
}

// ---------- shared-memory union (64 KiB): 2 blocks/CU guaranteed ----------
struct SG16 { u16 a[2][128 * 64]; u16 b[2][128 * 64]; };   // 64 KiB
struct SG32 { u16 a[2][64 * 128]; u16 b[2][64 * 128]; };   // 64 KiB
struct SAttn {
    u16 k[128][72];
    u16 v[64][152];
    u16 p[4][16][104];
    float bias[64];
};                                                          // ~50 KiB
union SMem { SG16 g16; SG32 g32; SAttn at; };
static_assert(sizeof(SMem) == 65536, "smem union must be 64KiB");

// ---------- fence-free grid barrier ----------
// R1/R2 lesson: per-block agent fences lower to buffer_wbl2 / buffer_inv —
// 512 full-L2 scans per barrier (~35us each). Scheme now: ALL inter-phase
// stores are agent-scope relaxed atomics (write-through to MALL, never dirty
// in L2); every inter-phase buffer is single-writer-then-read (no read ever
// precedes its write, so no stale L2 line can exist) -> plain cached loads
// are safe and the barrier needs NO cache maintenance at all.
__device__ __forceinline__ void gbar(unsigned* c, unsigned tgt) {
    __syncthreads();   // compiler drains vmcnt(0) before s_barrier
    if (threadIdx.x == 0) {
        __hip_atomic_fetch_add(c, 1u, __ATOMIC_RELAXED, __HIP_MEMORY_SCOPE_AGENT);
        while (__hip_atomic_load(c, __ATOMIC_RELAXED, __HIP_MEMORY_SCOPE_AGENT) < tgt)
            __builtin_amdgcn_s_sleep(4);
    }
    __syncthreads();
}

// ---------- wave-per-row LN (C=512): 8 elems/lane, shuffle-only ----------
__device__ __forceinline__ void ln_row_wave_f32(const float* __restrict__ x,
                                                const float* __restrict__ w,
                                                const float* __restrict__ b,
                                                u16* __restrict__ out, int row) {
    int lane = threadIdx.x & 63;
    const float4* xr = (const float4*)(x + (size_t)row * 512);
    float4 v0 = xr[lane * 2], v1 = xr[lane * 2 + 1];
    float s = v0.x + v0.y + v0.z + v0.w + v1.x + v1.y + v1.z + v1.w;
    float s2 = v0.x * v0.x + v0.y * v0.y + v0.z * v0.z + v0.w * v0.w +
               v1.x * v1.x + v1.y * v1.y + v1.z * v1.z + v1.w * v1.w;
    #pragma unroll
    for (int o = 32; o > 0; o >>= 1) {
        s += __shfl_xor(s, o, 64);
        s2 += __shfl_xor(s2, o, 64);
    }
    float mu = s * (1.0f / 512.0f);
    float var = s2 * (1.0f / 512.0f) - mu * mu;
    float rstd = rsqrtf(var + 1e-5f);
    const float4* wr = (const float4*)w;
    const float4* br = (const float4*)b;
    float4 w0 = wr[lane * 2], w1 = wr[lane * 2 + 1];
    float4 b0 = br[lane * 2], b1 = br[lane * 2 + 1];
    uint4 o4;
    o4.x = (uint)f2b((v0.x - mu) * rstd * w0.x + b0.x) |
           ((uint)f2b((v0.y - mu) * rstd * w0.y + b0.y) << 16);
    o4.y = (uint)f2b((v0.z - mu) * rstd * w0.z + b0.z) |
           ((uint)f2b((v0.w - mu) * rstd * w0.w + b0.w) << 16);
    o4.z = (uint)f2b((v1.x - mu) * rstd * w1.x + b1.x) |
           ((uint)f2b((v1.y - mu) * rstd * w1.y + b1.y) << 16);
    o4.w = (uint)f2b((v1.z - mu) * rstd * w1.z + b1.z) |
           ((uint)f2b((v1.w - mu) * rstd * w1.w + b1.w) << 16);
    ull* op = (ull*)(out + (size_t)row * 512);
    ST_AGENT(op + lane * 2,     (ull)o4.x | ((ull)o4.y << 32));
    ST_AGENT(op + lane * 2 + 1, (ull)o4.z | ((ull)o4.w << 32));
}

__device__ __forceinline__ void ln_row_wave_b16(const u16* __restrict__ x,
                                                const float* __restrict__ w,
                                                const float* __restrict__ b,
                                                u16* __restrict__ out, int row) {
    int lane = threadIdx.x & 63;
    uint4 p = ((const uint4*)(x + (size_t)row * 512))[lane];
    float v[8];
    v[0] = b2f((u16)(p.x & 0xffffu)); v[1] = b2f((u16)(p.x >> 16));
    v[2] = b2f((u16)(p.y & 0xffffu)); v[3] = b2f((u16)(p.y >> 16));
    v[4] = b2f((u16)(p.z & 0xffffu)); v[5] = b2f((u16)(p.z >> 16));
    v[6] = b2f((u16)(p.w & 0xffffu)); v[7] = b2f((u16)(p.w >> 16));
    float s = 0.f, s2 = 0.f;
    #pragma unroll
    for (int i = 0; i < 8; i++) { s += v[i]; s2 += v[i] * v[i]; }
    #pragma unroll
    for (int o = 32; o > 0; o >>= 1) {
        s += __shfl_xor(s, o, 64);
        s2 += __shfl_xor(s2, o, 64);
    }
    float mu = s * (1.0f / 512.0f);
    float var = s2 * (1.0f / 512.0f) - mu * mu;
    float rstd = rsqrtf(var + 1e-5f);
    const float4* wr = (const float4*)w;
    const float4* br = (const float4*)b;
    float4 w0 = wr[lane * 2], w1 = wr[lane * 2 + 1];
    float4 b0 = br[lane * 2], b1 = br[lane * 2 + 1];
    float o8[8];
    o8[0] = (v[0] - mu) * rstd * w0.x + b0.x;
    o8[1] = (v[1] - mu) * rstd * w0.y + b0.y;
    o8[2] = (v[2] - mu) * rstd * w0.z + b0.z;
    o8[3] = (v[3] - mu) * rstd * w0.w + b0.w;
    o8[4] = (v[4] - mu) * rstd * w1.x + b1.x;
    o8[5] = (v[5] - mu) * rstd * w1.y + b1.y;
    o8[6] = (v[6] - mu) * rstd * w1.z + b1.z;
    o8[7] = (v[7] - mu) * rstd * w1.w + b1.w;
    uint4 o4;
    o4.x = (uint)f2b(o8[0]) | ((uint)f2b(o8[1]) << 16);
    o4.y = (uint)f2b(o8[2]) | ((uint)f2b(o8[3]) << 16);
    o4.z = (uint)f2b(o8[4]) | ((uint)f2b(o8[5]) << 16);
    o4.w = (uint)f2b(o8[6]) | ((uint)f2b(o8[7]) << 16);
    ull* op = (ull*)(out + (size_t)row * 512);
    ST_AGENT(op + lane * 2,     (ull)o4.x | ((ull)o4.y << 32));
    ST_AGENT(op + lane * 2 + 1, (ull)o4.z | ((ull)o4.w << 32));
}

// ---------- prep: cvt 4 weights + LN1 ----------
__device__ __forceinline__ void prep_body(
    int bi, const float* __restrict__ qkvw, u16* __restrict__ wq,
    const float* __restrict__ projw, u16* __restrict__ wp,
    const float* __restrict__ fc1w, u16* __restrict__ w1,
    const float* __restrict__ fc2w, u16* __restrict__ w2,
    const float* __restrict__ x, const float* __restrict__ n1w,
    const float* __restrict__ n1b, u16* __restrict__ hb1) {
    if (bi < 3072) {
        const float* src;
        u16* dst;
        int i0;
        if (bi < 768)       { src = qkvw; dst = wq; i0 = bi; }
        else if (bi < 1024) { src = projw; dst = wp; i0 = bi - 768; }
        else if (bi < 2048) { src = fc1w; dst = w1; i0 = bi - 1024; }
        else                { src = fc2w; dst = w2; i0 = bi - 2048; }
        int i = i0 * 256 + threadIdx.x;
        float4 v = ((const float4*)src)[i];
        uint lo = (uint)f2b(v.x) | ((uint)f2b(v.y) << 16);
        uint hi = (uint)f2b(v.z) | ((uint)f2b(v.w) << 16);
        ST_AGENT((ull*)dst + i, (ull)lo | ((ull)hi << 32));
    } else {
        int row = (bi - 3072) * 4 + (threadIdx.x >> 6);
        ln_row_wave_f32(x, n1w, n1b, hb1, row);
    }
}

// ---------- GEMM A: 16x16x32 MFMA, MI=NI=4 frag reuse, dbuf, 128x128 BK=64 ----
// EPI: 0 bias->bf16 | 2 bias+GELU->bf16.  Coherent pair-packed stores.
template <int EPI>
__device__ __forceinline__ void gemm16_body(SMem& sm, int bx, int by,
                                            const u16* __restrict__ A,
                                            const u16* __restrict__ W,
                                            const float* __restrict__ bias,
                                            u16* __restrict__ outB,
                                            int M, int Nn, int K) {
    constexpr int BM = 128, BN = 128, BK = 64;
    int tid = threadIdx.x;
    int wid = tid >> 6, lane = tid & 63;
    int wm = wid >> 1, wn = wid & 1;
    int m_blk = bx * BM;
    int n_blk = by * BN;
    int lr = lane & 15;
    int lkc = lane >> 4;

    floatx4 acc[4][4];
    #pragma unroll
    for (int i = 0; i < 4; i++)
        #pragma unroll
        for (int j = 0; j < 4; j++) acc[i][j] = (floatx4){0.f, 0.f, 0.f, 0.f};

    const u16* Ag = A + (size_t)m_blk * K;
    const u16* Wg = W + (size_t)n_blk * K;

    int srow = tid >> 3;
    int skc = (tid & 7) ^ (srow & 7);

    auto stage = [&](int k0, int buf) {
        #pragma unroll
        for (int p = 0; p < 4; p++)
            gl_lds16(Ag + (size_t)(p * 32 + srow) * K + k0 + skc * 8,
                     sm.g16.a[buf] + (p * 256 + tid) * 8);
        #pragma unroll
        for (int p = 0; p < 4; p++)
            gl_lds16(Wg + (size_t)(p * 32 + srow) * K + k0 + skc * 8,
                     sm.g16.b[buf] + (p * 256 + tid) * 8);
    };

    stage(0, 0);
    int nit = K >> 6;
    for (int it = 0; it < nit; it++) {
        __syncthreads();
        if (it + 1 < nit) stage((it + 1) << 6, (it + 1) & 1);
        int cb = it & 1;
        #pragma unroll
        for (int s = 0; s < 2; s++) {
            int kc = s * 4 + lkc;
            shortx8 af[4], bf[4];
            #pragma unroll
            for (int i = 0; i < 4; i++) {
                int row = wm * 64 + i * 16 + lr;
                af[i] = *(const shortx8*)(sm.g16.a[cb] + (row * 8 + (kc ^ (row & 7))) * 8);
            }
            #pragma unroll
            for (int j = 0; j < 4; j++) {
                int row = wn * 64 + j * 16 + lr;
                bf[j] = *(const shortx8*)(sm.g16.b[cb] + (row * 8 + (kc ^ (row & 7))) * 8);
            }
            #pragma unroll
            for (int i = 0; i < 4; i++)
                #pragma unroll
                for (int j = 0; j < 4; j++)
                    acc[i][j] = __builtin_amdgcn_mfma_f32_16x16x32_bf16(
                        af[i], bf[j], acc[i][j], 0, 0, 0);
        }
    }

    // C/D: col = lane&15, row = (lane>>4)*4 + r.  Pack cols 2k/2k+1 across
    // lane^1, even lanes store r=0,1 / odd lanes r=2,3 (coherent 32-bit).
    int col_l = lane & 15;
    int row_base = (lane >> 4) * 4;
    int rsel = (lane & 1) * 2;
    #pragma unroll
    for (int nj = 0; nj < 4; nj++) {
        int col = n_blk + wn * 64 + nj * 16 + col_l;
        float bv = bias[col];
        #pragma unroll
        for (int mi = 0; mi < 4; mi++) {
            uint pw[4];
            #pragma unroll
            for (int r = 0; r < 4; r++) {
                float v = acc[mi][nj][r] + bv;
                pw[r] = pack_pair((uint)f2b(EPI == 2 ? gelu_f(v) : v), lane);
            }
            #pragma unroll
            for (int q = 0; q < 2; q++) {
                int r = rsel + q;
                int row = m_blk + wm * 64 + mi * 16 + row_base + r;
                ST_AGENT((uint*)(outB + (size_t)row * Nn + (col & ~1)), pw[r]);
            }
        }
    }
}

// ---------- GEMM B: 32x32x16, 64x64 block, BK=128, dbuf (N=512 GEMMs) ----------
// EPI: 1 bias+residF32->bf16 (coherent packed) | 3 bias+residB16->fp32 (final out)
template <int EPI>
__device__ __forceinline__ void gemm32_body(SMem& sm, int bx, int by,
                                            const u16* __restrict__ A,
                                            const u16* __restrict__ W,
                                            const float* __restrict__ bias,
                                            const float* __restrict__ residF,
                                            const u16* __restrict__ residB,
                                            float* __restrict__ outF,
                                            u16* __restrict__ outB,
                                            int M, int Nn, int K) {
    constexpr int BM = 64, BN = 64, BK = 128;
    constexpr int CPR = BK / 8, KMSK = CPR - 1;
    int tid = threadIdx.x;
    int wid = tid >> 6, lane = tid & 63;
    int wm = wid >> 1, wn = wid & 1;
    int m_blk = bx * BM;
    int n_blk = by * BN;
    int lr = lane & 31;
    int lk = lane >> 5;

    floatx16 acc;
    #pragma unroll
    for (int r = 0; r < 16; r++) acc[r] = 0.f;

    const u16* Ag = A + (size_t)m_blk * K;
    const u16* Wg = W + (size_t)n_blk * K;

    int srow = tid / CPR;
    int skc = (tid & KMSK) ^ (srow & KMSK);

    auto stage = [&](int k0, int buf) {
        #pragma unroll
        for (int p = 0; p < 4; p++)
            gl_lds16(Ag + (size_t)(p * 16 + srow) * K + k0 + skc * 8,
                     sm.g32.a[buf] + (p * 256 + tid) * 8);
        #pragma unroll
        for (int p = 0; p < 4; p++)
            gl_lds16(Wg + (size_t)(p * 16 + srow) * K + k0 + skc * 8,
                     sm.g32.b[buf] + (p * 256 + tid) * 8);
    };

    stage(0, 0);
    int nit = K / BK;
    for (int it = 0; it < nit; it++) {
        __syncthreads();
        if (it + 1 < nit) stage((it + 1) * BK, (it + 1) & 1);
        int cb = it & 1;
        #pragma unroll
        for (int s = 0; s < BK / 16; s++) {
            int kc = s * 2 + lk;
            int arow = wm * 32 + lr;
            int brow = wn * 32 + lr;
            shortx8 af = *(const shortx8*)(sm.g32.a[cb] + (arow * CPR + (kc ^ (arow & KMSK))) * 8);
            shortx8 bf = *(const shortx8*)(sm.g32.b[cb] + (brow * CPR + (kc ^ (brow & KMSK))) * 8);
            acc = __builtin_amdgcn_mfma_f32_32x32x16_bf16(af, bf, acc, 0, 0, 0);
        }
    }

    int col_l = lane & 31;
    int row_q = 4 * (lane >> 5);
    int col = n_blk + wn * 32 + col_l;
    float bv = bias[col];
    #pragma unroll
    for (int r = 0; r < 16; r++) {
        int row = m_blk + wm * 32 + (r & 3) + 8 * (r >> 2) + row_q;
        size_t off = (size_t)row * Nn + col;
        float v = acc[r] + bv;
        if (EPI == 1) {
            uint pw = pack_pair((uint)f2b(v + residF[off]), lane);
            if ((r & 1) == (lane & 1))
                ST_AGENT((uint*)(outB + (size_t)row * Nn + (col & ~1)), pw);
        } else {
            outF[off] = v + b2f(residB[off]);   // final output: plain store
        }
    }
}

// ---------- windowed attention, MFMA flash-style ----------
__device__ __forceinline__ void attn_body(SMem& sm, int bxx,
                                          const u16* __restrict__ qkv,
                                          const float* __restrict__ rel_bias,
                                          u16* __restrict__ out) {
    int n = bxx >> 8;
    int h = (bxx >> 5) & 7;
    int t0 = (bxx & 31) << 6;
    int tid = threadIdx.x, wid = tid >> 6, lane = tid & 63;
    int col = lane & 15, rq = lane >> 4;

    const u16* qrow = qkv + (size_t)(n * 2048 + t0 + wid * 16 + col) * 1536 + h * 64 + rq * 8;
    shortx8 qf0 = *(const shortx8*)qrow;
    shortx8 qf1 = *(const shortx8*)(qrow + 32);

    if (tid < 63) sm.at.bias[tid] = rel_bias[h * 63 + tid];
    if (tid == 63) sm.at.bias[63] = 0.f;

    const uint* qkv_u = (const uint*)qkv;
    // K tile: vectorized uint2 loads (8B/lane), 8 iters
    for (int idx = tid; idx < 128 * 16; idx += 256) {
        int row = idx >> 4, j2 = idx & 15;
        int pos = t0 - 31 + row;
        uint2 kv; kv.x = 0u; kv.y = 0u;
        if (pos >= 0 && pos < 2048)
            kv = *(const uint2*)(qkv_u + (size_t)(n * 2048 + pos) * 768 + 256 + h * 32 + j2 * 2);
        *(uint2*)&sm.at.k[row][j2 * 4] = kv;
    }
    // V transpose: row-pairs, packed b32 LDS writes
    for (int idx = tid; idx < 72 * 32; idx += 256) {
        int rp = idx >> 5, j = idx & 31;
        int r0 = rp * 2;
        int p0 = t0 - 31 + r0, p1 = p0 + 1;
        uint a = 0u, b = 0u;
        if (p0 >= 0 && p0 < 2048)
            a = qkv_u[(size_t)(n * 2048 + p0) * 768 + 512 + h * 32 + j];
        if (p1 >= 0 && p1 < 2048)
            b = qkv_u[(size_t)(n * 2048 + p1) * 768 + 512 + h * 32 + j];
        *(uint*)&sm.at.v[2 * j][r0]     = (a & 0xffffu) | (b << 16);
        *(uint*)&sm.at.v[2 * j + 1][r0] = (a >> 16) | (b & 0xffff0000u);
    }
    __syncthreads();

    floatx4 S[5];
    #pragma unroll
    for (int nt = 0; nt < 5; nt++) S[nt] = (floatx4){0.f, 0.f, 0.f, 0.f};
    #pragma unroll
    for (int nt = 0; nt < 5; nt++) {
        const u16* kb = &sm.at.k[wid * 16 + nt * 16 + col][rq * 8];
        shortx8 b0 = *(const shortx8*)kb;
        shortx8 b1 = *(const shortx8*)(kb + 32);
        S[nt] = __builtin_amdgcn_mfma_f32_16x16x32_bf16(qf0, b0, S[nt], 0, 0, 0);
        S[nt] = __builtin_amdgcn_mfma_f32_16x16x32_bf16(qf1, b1, S[nt], 0, 0, 0);
    }

    #pragma unroll
    for (int r = 0; r < 4; r++) {
        int t_row = rq * 4 + r;
        float sc[5];
        float mx = -1e30f;
        #pragma unroll
        for (int nt = 0; nt < 5; nt++) {
            int w = nt * 16 + col - t_row;
            int pos_abs = t0 - 31 + wid * 16 + nt * 16 + col;
            float v;
            if (w < 0 || w > 62) {
                v = -1e30f;
            } else {
                v = S[nt][r] * 0.125f + sm.at.bias[w];
                if (pos_abs < 0 || pos_abs >= 2048) v -= 100.f;
            }
            sc[nt] = v;
            mx = fmaxf(mx, v);
        }
        #pragma unroll
        for (int o = 1; o < 16; o <<= 1) mx = fmaxf(mx, __shfl_xor(mx, o, 64));
        float l = 0.f;
        #pragma unroll
        for (int nt = 0; nt < 5; nt++) {
            sc[nt] = __expf(sc[nt] - mx);
            l += sc[nt];
        }
        #pragma unroll
        for (int o = 1; o < 16; o <<= 1) l += __shfl_xor(l, o, 64);
        float inv = 1.0f / l;
        #pragma unroll
        for (int nt = 0; nt < 5; nt++)
            sm.at.p[wid][t_row][nt * 16 + col] = f2b(sc[nt] * inv);
        sm.at.p[wid][t_row][80 + col] = 0;
    }
    __syncthreads();

    floatx4 O[4];
    #pragma unroll
    for (int dt = 0; dt < 4; dt++) O[dt] = (floatx4){0.f, 0.f, 0.f, 0.f};
    const u16* pr = &sm.at.p[wid][col][rq * 8];
    shortx8 a0 = *(const shortx8*)pr;
    shortx8 a1 = *(const shortx8*)(pr + 32);
    shortx8 a2 = *(const shortx8*)(pr + 64);
    #pragma unroll
    for (int dt = 0; dt < 4; dt++) {
        const u16* vb = &sm.at.v[dt * 16 + col][wid * 16 + rq * 8];
        shortx8 b0 = *(const shortx8*)vb;
        shortx8 b1 = *(const shortx8*)(vb + 32);
        shortx8 b2 = *(const shortx8*)(vb + 64);
        O[dt] = __builtin_amdgcn_mfma_f32_16x16x32_bf16(a0, b0, O[dt], 0, 0, 0);
        O[dt] = __builtin_amdgcn_mfma_f32_16x16x32_bf16(a1, b1, O[dt], 0, 0, 0);
        O[dt] = __builtin_amdgcn_mfma_f32_16x16x32_bf16(a2, b2, O[dt], 0, 0, 0);
    }

    // coherent pair-packed stores: cols 2k/2k+1 across lane^1
    #pragma unroll
    for (int dt = 0; dt < 4; dt++) {
        #pragma unroll
        for (int r = 0; r < 4; r++) {
            int t_row = rq * 4 + r;
            uint pw = pack_pair((uint)f2b(O[dt][r]), lane);
            if ((r & 1) == (lane & 1))
                ST_AGENT((uint*)(out + (size_t)(n * 2048 + t0 + wid * 16 + t_row) * 512 +
                                 h * 64 + dt * 16 + (col & ~1)), pw);
        }
    }
}

// ---------- fused persistent kernel: whole layer, 7 phases, 6 grid barriers ----
__global__ __launch_bounds__(256, 2) void fused_layer(
    const float* __restrict__ x, const float* __restrict__ n1w,
    const float* __restrict__ n1b, const float* __restrict__ qkvw,
    const float* __restrict__ qkvbv, const float* __restrict__ relb,
    const float* __restrict__ projw, const float* __restrict__ projb,
    const float* __restrict__ n2w, const float* __restrict__ n2b,
    const float* __restrict__ fc1w, const float* __restrict__ fc1b,
    const float* __restrict__ fc2w, const float* __restrict__ fc2b,
    float* __restrict__ out,
    u16* __restrict__ wq, u16* __restrict__ wp, u16* __restrict__ w1,
    u16* __restrict__ w2, u16* __restrict__ hb1, u16* __restrict__ hb2,
    u16* __restrict__ qkvb, u16* __restrict__ attb, u16* __restrict__ x2b,
    u16* __restrict__ mb, unsigned* __restrict__ ctrs) {
    __shared__ SMem sm;
    int b = blockIdx.x;

    // phase 0: weight cvt + LN1 (4096 vblocks)
    for (int vb = b; vb < 4096; vb += 512)
        prep_body(vb, qkvw, wq, projw, wp, fc1w, w1, fc2w, w2, x, n1w, n1b, hb1);
    gbar(&ctrs[0], 512);

    // phase 1: qkv = hb1 @ wq^T + b   (4096x1536, K=512) — 384 vblocks
    if (b < 384)
        gemm16_body<0>(sm, b & 31, b >> 5, hb1, wq, qkvbv, qkvb, 4096, 1536, 512);
    gbar(&ctrs[1], 512);

    // phase 2: windowed attention — 512 vblocks
    attn_body(sm, b, qkvb, relb, attb);
    gbar(&ctrs[2], 512);

    // phase 3: x2 = x + attb @ wp^T + b  (4096x512, K=512) — 512 vblocks
    gemm32_body<1>(sm, b & 63, b >> 6, attb, wp, projb, x, nullptr,
                   nullptr, x2b, 4096, 512, 512);
    gbar(&ctrs[3], 512);

    // phase 4: LN2 (1024 vblocks x 4 rows) — writes hb2 (fresh buffer:
    // hb1 was read in phase 1, rewriting it would leave stale L2 lines)
    for (int vb = b; vb < 1024; vb += 512) {
        int row = vb * 4 + (threadIdx.x >> 6);
        ln_row_wave_b16(x2b, n2w, n2b, hb2, row);
    }
    gbar(&ctrs[4], 512);

    // phase 5: mb = gelu(hb2 @ w1^T + b)  (4096x2048, K=512) — 512 vblocks
    gemm16_body<2>(sm, b & 31, b >> 5, hb2, w1, fc1b, mb, 4096, 2048, 512);
    gbar(&ctrs[5], 512);

    // phase 6: out = x2 + mb @ w2^T + b  (4096x512, K=2048) — 512 vblocks
    gemm32_body<3>(sm, b & 63, b >> 6, mb, w2, fc2b, nullptr, x2b,
                   out, nullptr, 4096, 512, 2048);
}

// ---------- launcher ----------
extern "C" void kernel_launch(void* const* d_in, const int* in_sizes, int n_in,
                              void* d_out, int out_size, void* d_ws, size_t ws_size,
                              hipStream_t stream) {
    const float* x     = (const float*)d_in[0];
    const float* n1w   = (const float*)d_in[1];
    const float* n1b   = (const float*)d_in[2];
    const float* qkvw  = (const float*)d_in[3];
    const float* qkvbv = (const float*)d_in[4];
    const float* relb  = (const float*)d_in[5];
    const float* projw = (const float*)d_in[6];
    const float* projb = (const float*)d_in[7];
    const float* n2w   = (const float*)d_in[8];
    const float* n2b   = (const float*)d_in[9];
    const float* fc1w  = (const float*)d_in[10];
    const float* fc1b  = (const float*)d_in[11];
    const float* fc2w  = (const float*)d_in[12];
    const float* fc2b  = (const float*)d_in[13];
    float* out = (float*)d_out;

    char* p = (char*)d_ws;
    u16* wq   = (u16*)p;  p += (size_t)786432 * 2;   // qkv_w bf16 (1536x512)
    u16* wp   = (u16*)p;  p += (size_t)262144 * 2;   // proj_w bf16 (512x512)
    u16* w1   = (u16*)p;  p += (size_t)1048576 * 2;  // fc1_w bf16 (2048x512)
    u16* w2   = (u16*)p;  p += (size_t)1048576 * 2;  // fc2_w bf16 (512x2048)
    u16* hb1  = (u16*)p;  p += (size_t)2097152 * 2;  // LN1 out bf16 (4096x512)
    u16* hb2  = (u16*)p;  p += (size_t)2097152 * 2;  // LN2 out bf16 (4096x512)
    u16* qkvb = (u16*)p;  p += (size_t)6291456 * 2;  // qkv bf16 (4096x1536)
    u16* attb = (u16*)p;  p += (size_t)2097152 * 2;  // attn out bf16 (4096x512)
    u16* x2b  = (u16*)p;  p += (size_t)2097152 * 2;  // x + proj(attn), bf16
    u16* mb   = (u16*)p;  p += (size_t)8388608 * 2;  // gelu(fc1) bf16 (4096x2048)
    unsigned* ctrs = (unsigned*)p;                   // 6 barrier counters

    hipMemsetAsync(ctrs, 0, 64, stream);
    fused_layer<<<512, 256, 0, stream>>>(x, n1w, n1b, qkvw, qkvbv, relb, projw,
                                         projb, n2w, n2b, fc1w, fc1b, fc2w, fc2b,
                                         out, wq, wp, w1, w2, hb1, hb2, qkvb,
                                         attb, x2b, mb, ctrs);
}

// Round 5
// 164.694 us; speedup vs baseline: 4.0086x; 1.7565x over previous
//
#include <hip/hip_runtime.h>

typedef unsigned short u16;
typedef unsigned int uint;
typedef __attribute__((ext_vector_type(4))) float floatx4;
typedef __attribute__((ext_vector_type(16))) float floatx16;
typedef __attribute__((ext_vector_type(8))) short shortx8;

// ---------- helpers ----------
__device__ __forceinline__ u16 f2b(float f) {
    unsigned int u = __float_as_uint(f);
    unsigned int r = (u + 0x7fffu + ((u >> 16) & 1u)) >> 16;
    return (u16)r;
}
__device__ __forceinline__ float b2f(u16 u) {
    return __uint_as_float(((unsigned int)u) << 16);
}
__device__ __forceinline__ void gl_lds16(const u16* g, u16* l) {
    __builtin_amdgcn_global_load_lds(
        (const __attribute__((address_space(1))) void*)g,
        (__attribute__((address_space(3))) void*)l, 16, 0, 0);
}
__device__ __forceinline__ float gelu_f(float v) {
    float e = __expf(1.59576912f * v * (1.0f + 0.044715f * v * v));
    return v * e / (e + 1.0f);
}

// ---------- wave-per-row LN (C=512): 8 elems/lane, shuffle-only ----------
__device__ __forceinline__ void ln_row_wave_f32(const float* __restrict__ x,
                                                const float* __restrict__ w,
                                                const float* __restrict__ b,
                                                u16* __restrict__ out, int row) {
    int lane = threadIdx.x & 63;
    const float4* xr = (const float4*)(x + (size_t)row * 512);
    float4 v0 = xr[lane * 2], v1 = xr[lane * 2 + 1];
    float s = v0.x + v0.y + v0.z + v0.w + v1.x + v1.y + v1.z + v1.w;
    float s2 = v0.x * v0.x + v0.y * v0.y + v0.z * v0.z + v0.w * v0.w +
               v1.x * v1.x + v1.y * v1.y + v1.z * v1.z + v1.w * v1.w;
    #pragma unroll
    for (int o = 32; o > 0; o >>= 1) {
        s += __shfl_xor(s, o, 64);
        s2 += __shfl_xor(s2, o, 64);
    }
    float mu = s * (1.0f / 512.0f);
    float var = s2 * (1.0f / 512.0f) - mu * mu;
    float rstd = rsqrtf(var + 1e-5f);
    const float4* wr = (const float4*)w;
    const float4* br = (const float4*)b;
    float4 w0 = wr[lane * 2], w1 = wr[lane * 2 + 1];
    float4 b0 = br[lane * 2], b1 = br[lane * 2 + 1];
    uint4 o4;
    o4.x = (uint)f2b((v0.x - mu) * rstd * w0.x + b0.x) |
           ((uint)f2b((v0.y - mu) * rstd * w0.y + b0.y) << 16);
    o4.y = (uint)f2b((v0.z - mu) * rstd * w0.z + b0.z) |
           ((uint)f2b((v0.w - mu) * rstd * w0.w + b0.w) << 16);
    o4.z = (uint)f2b((v1.x - mu) * rstd * w1.x + b1.x) |
           ((uint)f2b((v1.y - mu) * rstd * w1.y + b1.y) << 16);
    o4.w = (uint)f2b((v1.z - mu) * rstd * w1.z + b1.z) |
           ((uint)f2b((v1.w - mu) * rstd * w1.w + b1.w) << 16);
    ((uint4*)(out + (size_t)row * 512))[lane] = o4;
}

// ---------- LN2: bf16 input, wave-per-row, 4 rows/block ----------
__global__ __launch_bounds__(256) void ln_kernel_b(const u16* __restrict__ x,
                                                   const float* __restrict__ w,
                                                   const float* __restrict__ b,
                                                   u16* __restrict__ out) {
    int row = blockIdx.x * 4 + (threadIdx.x >> 6);
    int lane = threadIdx.x & 63;
    uint4 p = ((const uint4*)(x + (size_t)row * 512))[lane];
    float v[8];
    v[0] = b2f((u16)(p.x & 0xffffu)); v[1] = b2f((u16)(p.x >> 16));
    v[2] = b2f((u16)(p.y & 0xffffu)); v[3] = b2f((u16)(p.y >> 16));
    v[4] = b2f((u16)(p.z & 0xffffu)); v[5] = b2f((u16)(p.z >> 16));
    v[6] = b2f((u16)(p.w & 0xffffu)); v[7] = b2f((u16)(p.w >> 16));
    float s = 0.f, s2 = 0.f;
    #pragma unroll
    for (int i = 0; i < 8; i++) { s += v[i]; s2 += v[i] * v[i]; }
    #pragma unroll
    for (int o = 32; o > 0; o >>= 1) {
        s += __shfl_xor(s, o, 64);
        s2 += __shfl_xor(s2, o, 64);
    }
    float mu = s * (1.0f / 512.0f);
    float var = s2 * (1.0f / 512.0f) - mu * mu;
    float rstd = rsqrtf(var + 1e-5f);
    const float4* wr = (const float4*)w;
    const float4* br = (const float4*)b;
    float4 w0 = wr[lane * 2], w1 = wr[lane * 2 + 1];
    float4 b0 = br[lane * 2], b1 = br[lane * 2 + 1];
    float o8[8];
    o8[0] = (v[0] - mu) * rstd * w0.x + b0.x;
    o8[1] = (v[1] - mu) * rstd * w0.y + b0.y;
    o8[2] = (v[2] - mu) * rstd * w0.z + b0.z;
    o8[3] = (v[3] - mu) * rstd * w0.w + b0.w;
    o8[4] = (v[4] - mu) * rstd * w1.x + b1.x;
    o8[5] = (v[5] - mu) * rstd * w1.y + b1.y;
    o8[6] = (v[6] - mu) * rstd * w1.z + b1.z;
    o8[7] = (v[7] - mu) * rstd * w1.w + b1.w;
    uint4 o4;
    o4.x = (uint)f2b(o8[0]) | ((uint)f2b(o8[1]) << 16);
    o4.y = (uint)f2b(o8[2]) | ((uint)f2b(o8[3]) << 16);
    o4.z = (uint)f2b(o8[4]) | ((uint)f2b(o8[5]) << 16);
    o4.w = (uint)f2b(o8[6]) | ((uint)f2b(o8[7]) << 16);
    ((uint4*)(out + (size_t)row * 512))[lane] = o4;
}

// ---------- fused prep: cvt 4 weights + LN1 (wave-per-row) ----------
// blocks [0,3072): weight cvt | [3072,4096): LN1, 4 rows per block
__global__ __launch_bounds__(256) void prep_kernel(
    const float* __restrict__ qkvw, u16* __restrict__ wq,
    const float* __restrict__ projw, u16* __restrict__ wp,
    const float* __restrict__ fc1w, u16* __restrict__ w1,
    const float* __restrict__ fc2w, u16* __restrict__ w2,
    const float* __restrict__ x, const float* __restrict__ n1w,
    const float* __restrict__ n1b, u16* __restrict__ hb) {
    int bi = blockIdx.x;
    if (bi < 3072) {
        const float* src;
        u16* dst;
        int i0;
        if (bi < 768)       { src = qkvw; dst = wq; i0 = bi; }
        else if (bi < 1024) { src = projw; dst = wp; i0 = bi - 768; }
        else if (bi < 2048) { src = fc1w; dst = w1; i0 = bi - 1024; }
        else                { src = fc2w; dst = w2; i0 = bi - 2048; }
        int i = i0 * 256 + threadIdx.x;
        float4 v = ((const float4*)src)[i];
        uint2 o;
        o.x = (uint)f2b(v.x) | ((uint)f2b(v.y) << 16);
        o.y = (uint)f2b(v.z) | ((uint)f2b(v.w) << 16);
        ((uint2*)dst)[i] = o;
    } else {
        int row = (bi - 3072) * 4 + (threadIdx.x >> 6);
        ln_row_wave_f32(x, n1w, n1b, hb, row);
    }
}

// ---------- GEMM A: 16x16x32 MFMA, MI=NI=4 (m97 frag reuse), dbuf ----------
// 128x128 block, BK=64, 2x2 waves, wave tile 64x64 as 4x4 16-tiles.
// reads/MFMA = 0.5 (each frag feeds 4 MFMAs). EPI: 0 bias->bf16 | 2 bias+GELU->bf16
// R9 lesson: dbuf@2blk/CU beats single-buf@3-4blk/CU.
template <int EPI>
__global__ __launch_bounds__(256, 2) void gemm16(const u16* __restrict__ A,
                                                 const u16* __restrict__ W,
                                                 const float* __restrict__ bias,
                                                 u16* __restrict__ outB,
                                                 int M, int Nn, int K) {
    constexpr int BM = 128, BN = 128, BK = 64;
    __shared__ u16 a_s[2][BM * BK];
    __shared__ u16 b_s[2][BN * BK];

    int tid = threadIdx.x;
    int wid = tid >> 6, lane = tid & 63;
    int wm = wid >> 1, wn = wid & 1;
    int m_blk = blockIdx.x * BM;          // m fastest: same-XCD blocks share B-strip
    int n_blk = blockIdx.y * BN;
    int lr = lane & 15;
    int lkc = lane >> 4;                  // 0..3

    floatx4 acc[4][4];
    #pragma unroll
    for (int i = 0; i < 4; i++)
        #pragma unroll
        for (int j = 0; j < 4; j++) acc[i][j] = (floatx4){0.f, 0.f, 0.f, 0.f};

    const u16* Ag = A + (size_t)m_blk * K;
    const u16* Wg = W + (size_t)n_blk * K;

    int srow = tid >> 3;                  // staging: 4 chunks/thread, rows of 8 chunks
    int skc = (tid & 7) ^ (srow & 7);

    auto stage = [&](int k0, int buf) {
        #pragma unroll
        for (int p = 0; p < 4; p++)
            gl_lds16(Ag + (size_t)(p * 32 + srow) * K + k0 + skc * 8,
                     a_s[buf] + (p * 256 + tid) * 8);
        #pragma unroll
        for (int p = 0; p < 4; p++)
            gl_lds16(Wg + (size_t)(p * 32 + srow) * K + k0 + skc * 8,
                     b_s[buf] + (p * 256 + tid) * 8);
    };

    stage(0, 0);
    int nit = K >> 6;
    for (int it = 0; it < nit; it++) {
        __syncthreads();
        if (it + 1 < nit) stage((it + 1) << 6, (it + 1) & 1);
        int cb = it & 1;
        #pragma unroll
        for (int s = 0; s < 2; s++) {     // two K=32 sub-tiles
            int kc = s * 4 + lkc;
            shortx8 af[4], bf[4];
            #pragma unroll
            for (int i = 0; i < 4; i++) {
                int row = wm * 64 + i * 16 + lr;
                af[i] = *(const shortx8*)(a_s[cb] + (row * 8 + (kc ^ (row & 7))) * 8);
            }
            #pragma unroll
            for (int j = 0; j < 4; j++) {
                int row = wn * 64 + j * 16 + lr;
                bf[j] = *(const shortx8*)(b_s[cb] + (row * 8 + (kc ^ (row & 7))) * 8);
            }
            #pragma unroll
            for (int i = 0; i < 4; i++)
                #pragma unroll
                for (int j = 0; j < 4; j++)
                    acc[i][j] = __builtin_amdgcn_mfma_f32_16x16x32_bf16(
                        af[i], bf[j], acc[i][j], 0, 0, 0);
        }
    }

    // C/D: col = lane&15, row = (lane>>4)*4 + r
    int col_l = lane & 15;
    int row_base = (lane >> 4) * 4;
    #pragma unroll
    for (int nj = 0; nj < 4; nj++) {
        int col = n_blk + wn * 64 + nj * 16 + col_l;
        float bv = bias[col];
        #pragma unroll
        for (int mi = 0; mi < 4; mi++) {
            #pragma unroll
            for (int r = 0; r < 4; r++) {
                int row = m_blk + wm * 64 + mi * 16 + row_base + r;
                size_t off = (size_t)row * Nn + col;
                float v = acc[mi][nj][r] + bv;
                outB[off] = f2b(EPI == 2 ? gelu_f(v) : v);
            }
        }
    }
}

// ---------- GEMM B: 32x32x16, 64x64 block, BK=128, dbuf (N=512 GEMMs) ----------
// EPI: 1 bias+residF32->bf16 | 3 bias+residB16->fp32 (d_out)
template <int EPI>
__global__ __launch_bounds__(256, 2) void gemm32(const u16* __restrict__ A,
                                                 const u16* __restrict__ W,
                                                 const float* __restrict__ bias,
                                                 const float* __restrict__ residF,
                                                 const u16* __restrict__ residB,
                                                 float* __restrict__ outF,
                                                 u16* __restrict__ outB,
                                                 int M, int Nn, int K) {
    constexpr int BM = 64, BN = 64, BK = 128;
    constexpr int CPR = BK / 8, KMSK = CPR - 1;
    __shared__ u16 a_s[2][BM * BK];
    __shared__ u16 b_s[2][BN * BK];

    int tid = threadIdx.x;
    int wid = tid >> 6, lane = tid & 63;
    int wm = wid >> 1, wn = wid & 1;
    int m_blk = blockIdx.x * BM;
    int n_blk = blockIdx.y * BN;
    int lr = lane & 31;
    int lk = lane >> 5;

    floatx16 acc;
    #pragma unroll
    for (int r = 0; r < 16; r++) acc[r] = 0.f;

    const u16* Ag = A + (size_t)m_blk * K;
    const u16* Wg = W + (size_t)n_blk * K;

    int srow = tid / CPR;                 // 4 rows per 64 threads
    int skc = (tid & KMSK) ^ (srow & KMSK);

    auto stage = [&](int k0, int buf) {
        #pragma unroll
        for (int p = 0; p < 4; p++)
            gl_lds16(Ag + (size_t)(p * 16 + srow) * K + k0 + skc * 8,
                     a_s[buf] + (p * 256 + tid) * 8);
        #pragma unroll
        for (int p = 0; p < 4; p++)
            gl_lds16(Wg + (size_t)(p * 16 + srow) * K + k0 + skc * 8,
                     b_s[buf] + (p * 256 + tid) * 8);
    };

    stage(0, 0);
    int nit = K / BK;
    for (int it = 0; it < nit; it++) {
        __syncthreads();
        if (it + 1 < nit) stage((it + 1) * BK, (it + 1) & 1);
        int cb = it & 1;
        #pragma unroll
        for (int s = 0; s < BK / 16; s++) {
            int kc = s * 2 + lk;
            int arow = wm * 32 + lr;
            int brow = wn * 32 + lr;
            shortx8 af = *(const shortx8*)(a_s[cb] + (arow * CPR + (kc ^ (arow & KMSK))) * 8);
            shortx8 bf = *(const shortx8*)(b_s[cb] + (brow * CPR + (kc ^ (brow & KMSK))) * 8);
            acc = __builtin_amdgcn_mfma_f32_32x32x16_bf16(af, bf, acc, 0, 0, 0);
        }
    }

    int col_l = lane & 31;
    int row_q = 4 * (lane >> 5);
    int col = n_blk + wn * 32 + col_l;
    float bv = bias[col];
    #pragma unroll
    for (int r = 0; r < 16; r++) {
        int row = m_blk + wm * 32 + (r & 3) + 8 * (r >> 2) + row_q;
        size_t off = (size_t)row * Nn + col;
        float v = acc[r] + bv;
        if (EPI == 1) outB[off] = f2b(v + residF[off]);
        else          outF[off] = v + b2f(residB[off]);
    }
}

// ---------- windowed attention, MFMA flash-style ----------
// R1-verified staging: K tile as uint2 (8B/lane) loads; V transpose staged as
// row-pairs with packed b32 LDS writes (halves global-load + LDS-write insts).
__global__ __launch_bounds__(256) void attn_kernel(const u16* __restrict__ qkv,
                                                   const float* __restrict__ rel_bias,
                                                   u16* __restrict__ out) {
    __shared__ u16 k_s[128][72];
    __shared__ u16 v_t[64][152];
    __shared__ u16 p_s[4][16][104];
    __shared__ float s_bias[64];

    int bx = blockIdx.x;
    int n = bx >> 8;
    int h = (bx >> 5) & 7;
    int t0 = (bx & 31) << 6;
    int tid = threadIdx.x, wid = tid >> 6, lane = tid & 63;
    int col = lane & 15, rq = lane >> 4;

    const u16* qrow = qkv + (size_t)(n * 2048 + t0 + wid * 16 + col) * 1536 + h * 64 + rq * 8;
    shortx8 qf0 = *(const shortx8*)qrow;
    shortx8 qf1 = *(const shortx8*)(qrow + 32);

    if (tid < 63) s_bias[tid] = rel_bias[h * 63 + tid];
    if (tid == 63) s_bias[63] = 0.f;

    const uint* qkv_u = (const uint*)qkv;
    // K tile: vectorized uint2 loads (8B/lane), 8 iters
    for (int idx = tid; idx < 128 * 16; idx += 256) {
        int row = idx >> 4, j2 = idx & 15;
        int pos = t0 - 31 + row;
        uint2 kv; kv.x = 0u; kv.y = 0u;
        if (pos >= 0 && pos < 2048)
            kv = *(const uint2*)(qkv_u + (size_t)(n * 2048 + pos) * 768 + 256 + h * 32 + j2 * 2);
        *(uint2*)&k_s[row][j2 * 4] = kv;
    }
    // V transpose: row-pairs, packed b32 LDS writes
    for (int idx = tid; idx < 72 * 32; idx += 256) {
        int rp = idx >> 5, j = idx & 31;
        int r0 = rp * 2;
        int p0 = t0 - 31 + r0, p1 = p0 + 1;
        uint a = 0u, b = 0u;
        if (p0 >= 0 && p0 < 2048)
            a = qkv_u[(size_t)(n * 2048 + p0) * 768 + 512 + h * 32 + j];
        if (p1 >= 0 && p1 < 2048)
            b = qkv_u[(size_t)(n * 2048 + p1) * 768 + 512 + h * 32 + j];
        *(uint*)&v_t[2 * j][r0]     = (a & 0xffffu) | (b << 16);
        *(uint*)&v_t[2 * j + 1][r0] = (a >> 16) | (b & 0xffff0000u);
    }
    __syncthreads();

    floatx4 S[5];
    #pragma unroll
    for (int nt = 0; nt < 5; nt++) S[nt] = (floatx4){0.f, 0.f, 0.f, 0.f};
    #pragma unroll
    for (int nt = 0; nt < 5; nt++) {
        const u16* kb = &k_s[wid * 16 + nt * 16 + col][rq * 8];
        shortx8 b0 = *(const shortx8*)kb;
        shortx8 b1 = *(const shortx8*)(kb + 32);
        S[nt] = __builtin_amdgcn_mfma_f32_16x16x32_bf16(qf0, b0, S[nt], 0, 0, 0);
        S[nt] = __builtin_amdgcn_mfma_f32_16x16x32_bf16(qf1, b1, S[nt], 0, 0, 0);
    }

    #pragma unroll
    for (int r = 0; r < 4; r++) {
        int t_row = rq * 4 + r;
        float sc[5];
        float mx = -1e30f;
        #pragma unroll
        for (int nt = 0; nt < 5; nt++) {
            int w = nt * 16 + col - t_row;
            int pos_abs = t0 - 31 + wid * 16 + nt * 16 + col;
            float v;
            if (w < 0 || w > 62) {
                v = -1e30f;
            } else {
                v = S[nt][r] * 0.125f + s_bias[w];
                if (pos_abs < 0 || pos_abs >= 2048) v -= 100.f;
            }
            sc[nt] = v;
            mx = fmaxf(mx, v);
        }
        #pragma unroll
        for (int o = 1; o < 16; o <<= 1) mx = fmaxf(mx, __shfl_xor(mx, o, 64));
        float l = 0.f;
        #pragma unroll
        for (int nt = 0; nt < 5; nt++) {
            sc[nt] = __expf(sc[nt] - mx);
            l += sc[nt];
        }
        #pragma unroll
        for (int o = 1; o < 16; o <<= 1) l += __shfl_xor(l, o, 64);
        float inv = 1.0f / l;
        #pragma unroll
        for (int nt = 0; nt < 5; nt++)
            p_s[wid][t_row][nt * 16 + col] = f2b(sc[nt] * inv);
        p_s[wid][t_row][80 + col] = 0;
    }
    __syncthreads();

    floatx4 O[4];
    #pragma unroll
    for (int dt = 0; dt < 4; dt++) O[dt] = (floatx4){0.f, 0.f, 0.f, 0.f};
    const u16* pr = &p_s[wid][col][rq * 8];
    shortx8 a0 = *(const shortx8*)pr;
    shortx8 a1 = *(const shortx8*)(pr + 32);
    shortx8 a2 = *(const shortx8*)(pr + 64);
    #pragma unroll
    for (int dt = 0; dt < 4; dt++) {
        const u16* vb = &v_t[dt * 16 + col][wid * 16 + rq * 8];
        shortx8 b0 = *(const shortx8*)vb;
        shortx8 b1 = *(const shortx8*)(vb + 32);
        shortx8 b2 = *(const shortx8*)(vb + 64);
        O[dt] = __builtin_amdgcn_mfma_f32_16x16x32_bf16(a0, b0, O[dt], 0, 0, 0);
        O[dt] = __builtin_amdgcn_mfma_f32_16x16x32_bf16(a1, b1, O[dt], 0, 0, 0);
        O[dt] = __builtin_amdgcn_mfma_f32_16x16x32_bf16(a2, b2, O[dt], 0, 0, 0);
    }

    #pragma unroll
    for (int dt = 0; dt < 4; dt++) {
        #pragma unroll
        for (int r = 0; r < 4; r++) {
            int t_row = rq * 4 + r;
            out[(size_t)(n * 2048 + t0 + wid * 16 + t_row) * 512 + h * 64 + dt * 16 + col] =
                f2b(O[dt][r]);
        }
    }
}

// ---------- launcher ----------
extern "C" void kernel_launch(void* const* d_in, const int* in_sizes, int n_in,
                              void* d_out, int out_size, void* d_ws, size_t ws_size,
                              hipStream_t stream) {
    const float* x     = (const float*)d_in[0];
    const float* n1w   = (const float*)d_in[1];
    const float* n1b   = (const float*)d_in[2];
    const float* qkvw  = (const float*)d_in[3];
    const float* qkvbv = (const float*)d_in[4];
    const float* relb  = (const float*)d_in[5];
    const float* projw = (const float*)d_in[6];
    const float* projb = (const float*)d_in[7];
    const float* n2w   = (const float*)d_in[8];
    const float* n2b   = (const float*)d_in[9];
    const float* fc1w  = (const float*)d_in[10];
    const float* fc1b  = (const float*)d_in[11];
    const float* fc2w  = (const float*)d_in[12];
    const float* fc2b  = (const float*)d_in[13];
    float* out = (float*)d_out;

    char* p = (char*)d_ws;
    u16* wq   = (u16*)p;  p += (size_t)786432 * 2;   // qkv_w bf16 (1536x512)
    u16* wp   = (u16*)p;  p += (size_t)262144 * 2;   // proj_w bf16 (512x512)
    u16* w1   = (u16*)p;  p += (size_t)1048576 * 2;  // fc1_w bf16 (2048x512)
    u16* w2   = (u16*)p;  p += (size_t)1048576 * 2;  // fc2_w bf16 (512x2048)
    u16* hb   = (u16*)p;  p += (size_t)2097152 * 2;  // h / h2 bf16 (4096x512)
    u16* qkvb = (u16*)p;  p += (size_t)6291456 * 2;  // qkv bf16 (4096x1536)
    u16* attb = (u16*)p;  p += (size_t)2097152 * 2;  // attn out bf16 (4096x512)
    u16* x2b  = (u16*)p;  p += (size_t)2097152 * 2;  // x + proj(attn), bf16
    u16* mb   = (u16*)p;  p += (size_t)8388608 * 2;  // gelu(fc1) bf16 (4096x2048)

    prep_kernel<<<4096, 256, 0, stream>>>(qkvw, wq, projw, wp, fc1w, w1, fc2w, w2,
                                          x, n1w, n1b, hb);
    // qkv: 4096x1536, K=512; 16x16 MI=NI=4, grid m-fastest
    gemm16<0><<<dim3(32, 12), 256, 0, stream>>>(hb, wq, qkvbv, qkvb, 4096, 1536, 512);
    attn_kernel<<<512, 256, 0, stream>>>(qkvb, relb, attb);
    // proj: 4096x512, K=512; x2 = x + proj (bf16)
    gemm32<1><<<dim3(64, 8), 256, 0, stream>>>(attb, wp, projb, x, nullptr,
                                               nullptr, x2b, 4096, 512, 512);
    ln_kernel_b<<<1024, 256, 0, stream>>>(x2b, n2w, n2b, hb);
    // fc1: 4096x2048, K=512
    gemm16<2><<<dim3(32, 16), 256, 0, stream>>>(hb, w1, fc1b, mb, 4096, 2048, 512);
    // fc2: 4096x512, K=2048; out = x2 + fc2 (fp32)
    gemm32<3><<<dim3(64, 8), 256, 0, stream>>>(mb, w2, fc2b, nullptr, x2b,
                                               out, nullptr, 4096, 512, 2048);
}

// Round 6
// 164.676 us; speedup vs baseline: 4.0091x; 1.0001x over previous
//
#include <hip/hip_runtime.h>

typedef unsigned short u16;
typedef unsigned int uint;
typedef __attribute__((ext_vector_type(4))) float floatx4;
typedef __attribute__((ext_vector_type(16))) float floatx16;
typedef __attribute__((ext_vector_type(8))) short shortx8;

// ---------- helpers ----------
__device__ __forceinline__ u16 f2b(float f) {
    unsigned int u = __float_as_uint(f);
    unsigned int r = (u + 0x7fffu + ((u >> 16) & 1u)) >> 16;
    return (u16)r;
}
__device__ __forceinline__ float b2f(u16 u) {
    return __uint_as_float(((unsigned int)u) << 16);
}
__device__ __forceinline__ void gl_lds16(const u16* g, u16* l) {
    __builtin_amdgcn_global_load_lds(
        (const __attribute__((address_space(1))) void*)g,
        (__attribute__((address_space(3))) void*)l, 16, 0, 0);
}
__device__ __forceinline__ float gelu_f(float v) {
    float e = __expf(1.59576912f * v * (1.0f + 0.044715f * v * v));
    return v * e / (e + 1.0f);
}
// one 1024-float4 weight-cvt chunk (f32 -> bf16), 256 threads
__device__ __forceinline__ void cvt_block(const float* __restrict__ src,
                                          u16* __restrict__ dst, int i0) {
    int i = i0 * 256 + threadIdx.x;
    float4 v = ((const float4*)src)[i];
    uint2 o;
    o.x = (uint)f2b(v.x) | ((uint)f2b(v.y) << 16);
    o.y = (uint)f2b(v.z) | ((uint)f2b(v.w) << 16);
    ((uint2*)dst)[i] = o;
}

// ---------- wave-per-row LN (C=512): 8 elems/lane, shuffle-only ----------
__device__ __forceinline__ void ln_row_wave_f32(const float* __restrict__ x,
                                                const float* __restrict__ w,
                                                const float* __restrict__ b,
                                                u16* __restrict__ out, int row) {
    int lane = threadIdx.x & 63;
    const float4* xr = (const float4*)(x + (size_t)row * 512);
    float4 v0 = xr[lane * 2], v1 = xr[lane * 2 + 1];
    float s = v0.x + v0.y + v0.z + v0.w + v1.x + v1.y + v1.z + v1.w;
    float s2 = v0.x * v0.x + v0.y * v0.y + v0.z * v0.z + v0.w * v0.w +
               v1.x * v1.x + v1.y * v1.y + v1.z * v1.z + v1.w * v1.w;
    #pragma unroll
    for (int o = 32; o > 0; o >>= 1) {
        s += __shfl_xor(s, o, 64);
        s2 += __shfl_xor(s2, o, 64);
    }
    float mu = s * (1.0f / 512.0f);
    float var = s2 * (1.0f / 512.0f) - mu * mu;
    float rstd = rsqrtf(var + 1e-5f);
    const float4* wr = (const float4*)w;
    const float4* br = (const float4*)b;
    float4 w0 = wr[lane * 2], w1 = wr[lane * 2 + 1];
    float4 b0 = br[lane * 2], b1 = br[lane * 2 + 1];
    uint4 o4;
    o4.x = (uint)f2b((v0.x - mu) * rstd * w0.x + b0.x) |
           ((uint)f2b((v0.y - mu) * rstd * w0.y + b0.y) << 16);
    o4.y = (uint)f2b((v0.z - mu) * rstd * w0.z + b0.z) |
           ((uint)f2b((v0.w - mu) * rstd * w0.w + b0.w) << 16);
    o4.z = (uint)f2b((v1.x - mu) * rstd * w1.x + b1.x) |
           ((uint)f2b((v1.y - mu) * rstd * w1.y + b1.y) << 16);
    o4.w = (uint)f2b((v1.z - mu) * rstd * w1.z + b1.z) |
           ((uint)f2b((v1.w - mu) * rstd * w1.w + b1.w) << 16);
    ((uint4*)(out + (size_t)row * 512))[lane] = o4;
}

// ---------- LN2: bf16 input, wave-per-row, 4 rows/block ----------
__global__ __launch_bounds__(256) void ln_kernel_b(const u16* __restrict__ x,
                                                   const float* __restrict__ w,
                                                   const float* __restrict__ b,
                                                   u16* __restrict__ out) {
    int row = blockIdx.x * 4 + (threadIdx.x >> 6);
    int lane = threadIdx.x & 63;
    uint4 p = ((const uint4*)(x + (size_t)row * 512))[lane];
    float v[8];
    v[0] = b2f((u16)(p.x & 0xffffu)); v[1] = b2f((u16)(p.x >> 16));
    v[2] = b2f((u16)(p.y & 0xffffu)); v[3] = b2f((u16)(p.y >> 16));
    v[4] = b2f((u16)(p.z & 0xffffu)); v[5] = b2f((u16)(p.z >> 16));
    v[6] = b2f((u16)(p.w & 0xffffu)); v[7] = b2f((u16)(p.w >> 16));
    float s = 0.f, s2 = 0.f;
    #pragma unroll
    for (int i = 0; i < 8; i++) { s += v[i]; s2 += v[i] * v[i]; }
    #pragma unroll
    for (int o = 32; o > 0; o >>= 1) {
        s += __shfl_xor(s, o, 64);
        s2 += __shfl_xor(s2, o, 64);
    }
    float mu = s * (1.0f / 512.0f);
    float var = s2 * (1.0f / 512.0f) - mu * mu;
    float rstd = rsqrtf(var + 1e-5f);
    const float4* wr = (const float4*)w;
    const float4* br = (const float4*)b;
    float4 w0 = wr[lane * 2], w1 = wr[lane * 2 + 1];
    float4 b0 = br[lane * 2], b1 = br[lane * 2 + 1];
    float o8[8];
    o8[0] = (v[0] - mu) * rstd * w0.x + b0.x;
    o8[1] = (v[1] - mu) * rstd * w0.y + b0.y;
    o8[2] = (v[2] - mu) * rstd * w0.z + b0.z;
    o8[3] = (v[3] - mu) * rstd * w0.w + b0.w;
    o8[4] = (v[4] - mu) * rstd * w1.x + b1.x;
    o8[5] = (v[5] - mu) * rstd * w1.y + b1.y;
    o8[6] = (v[6] - mu) * rstd * w1.z + b1.z;
    o8[7] = (v[7] - mu) * rstd * w1.w + b1.w;
    uint4 o4;
    o4.x = (uint)f2b(o8[0]) | ((uint)f2b(o8[1]) << 16);
    o4.y = (uint)f2b(o8[2]) | ((uint)f2b(o8[3]) << 16);
    o4.z = (uint)f2b(o8[4]) | ((uint)f2b(o8[5]) << 16);
    o4.w = (uint)f2b(o8[6]) | ((uint)f2b(o8[7]) << 16);
    ((uint4*)(out + (size_t)row * 512))[lane] = o4;
}

// ---------- prep: cvt wq + LN1 only (wp/w1/w2 cvt moved into later grids) ----
// blocks [0,768): wq cvt | [768,1792): LN1, 4 rows per block
__global__ __launch_bounds__(256) void prep_kernel(
    const float* __restrict__ qkvw, u16* __restrict__ wq,
    const float* __restrict__ x, const float* __restrict__ n1w,
    const float* __restrict__ n1b, u16* __restrict__ hb) {
    int bi = blockIdx.x;
    if (bi < 768) {
        cvt_block(qkvw, wq, bi);
    } else {
        int row = (bi - 768) * 4 + (threadIdx.x >> 6);
        ln_row_wave_f32(x, n1w, n1b, hb, row);
    }
}

// ---------- GEMM A: 16x16x32 MFMA, MI=NI=4 (m97 frag reuse), dbuf ----------
// 128x128 block, BK=64, 2x2 waves, wave tile 64x64 as 4x4 16-tiles.
// reads/MFMA = 0.5. EPI: 0 bias->bf16 | 2 bias+GELU->bf16
// Grid rows by >= nby are weight-cvt tail blocks (overlap cvt with GEMM's
// spare HBM BW; dispatch is x-fastest so GEMM blocks launch first).
template <int EPI>
__global__ __launch_bounds__(256, 2) void gemm16(const u16* __restrict__ A,
                                                 const u16* __restrict__ W,
                                                 const float* __restrict__ bias,
                                                 u16* __restrict__ outB,
                                                 int M, int Nn, int K, int nby,
                                                 const float* __restrict__ cs0,
                                                 u16* __restrict__ cd0, int cn0,
                                                 const float* __restrict__ cs1,
                                                 u16* __restrict__ cd1, int cn1) {
    constexpr int BM = 128, BN = 128, BK = 64;
    __shared__ u16 a_s[2][BM * BK];
    __shared__ u16 b_s[2][BN * BK];

    if ((int)blockIdx.y >= nby) {
        int flat = ((int)blockIdx.y - nby) * (int)gridDim.x + (int)blockIdx.x;
        if (flat < cn0)            cvt_block(cs0, cd0, flat);
        else if (flat < cn0 + cn1) cvt_block(cs1, cd1, flat - cn0);
        return;
    }

    int tid = threadIdx.x;
    int wid = tid >> 6, lane = tid & 63;
    int wm = wid >> 1, wn = wid & 1;
    int m_blk = blockIdx.x * BM;          // m fastest: same-XCD blocks share B-strip
    int n_blk = blockIdx.y * BN;
    int lr = lane & 15;
    int lkc = lane >> 4;                  // 0..3

    floatx4 acc[4][4];
    #pragma unroll
    for (int i = 0; i < 4; i++)
        #pragma unroll
        for (int j = 0; j < 4; j++) acc[i][j] = (floatx4){0.f, 0.f, 0.f, 0.f};

    const u16* Ag = A + (size_t)m_blk * K;
    const u16* Wg = W + (size_t)n_blk * K;

    int srow = tid >> 3;                  // staging: 4 chunks/thread, rows of 8 chunks
    int skc = (tid & 7) ^ (srow & 7);

    auto stage = [&](int k0, int buf) {
        #pragma unroll
        for (int p = 0; p < 4; p++)
            gl_lds16(Ag + (size_t)(p * 32 + srow) * K + k0 + skc * 8,
                     a_s[buf] + (p * 256 + tid) * 8);
        #pragma unroll
        for (int p = 0; p < 4; p++)
            gl_lds16(Wg + (size_t)(p * 32 + srow) * K + k0 + skc * 8,
                     b_s[buf] + (p * 256 + tid) * 8);
    };

    stage(0, 0);
    int nit = K >> 6;
    for (int it = 0; it < nit; it++) {
        __syncthreads();
        if (it + 1 < nit) stage((it + 1) << 6, (it + 1) & 1);
        int cb = it & 1;
        #pragma unroll
        for (int s = 0; s < 2; s++) {     // two K=32 sub-tiles
            int kc = s * 4 + lkc;
            shortx8 af[4], bf[4];
            #pragma unroll
            for (int i = 0; i < 4; i++) {
                int row = wm * 64 + i * 16 + lr;
                af[i] = *(const shortx8*)(a_s[cb] + (row * 8 + (kc ^ (row & 7))) * 8);
            }
            #pragma unroll
            for (int j = 0; j < 4; j++) {
                int row = wn * 64 + j * 16 + lr;
                bf[j] = *(const shortx8*)(b_s[cb] + (row * 8 + (kc ^ (row & 7))) * 8);
            }
            #pragma unroll
            for (int i = 0; i < 4; i++)
                #pragma unroll
                for (int j = 0; j < 4; j++)
                    acc[i][j] = __builtin_amdgcn_mfma_f32_16x16x32_bf16(
                        af[i], bf[j], acc[i][j], 0, 0, 0);
        }
    }

    // C/D: col = lane&15, row = (lane>>4)*4 + r
    int col_l = lane & 15;
    int row_base = (lane >> 4) * 4;
    #pragma unroll
    for (int nj = 0; nj < 4; nj++) {
        int col = n_blk + wn * 64 + nj * 16 + col_l;
        float bv = bias[col];
        #pragma unroll
        for (int mi = 0; mi < 4; mi++) {
            #pragma unroll
            for (int r = 0; r < 4; r++) {
                int row = m_blk + wm * 64 + mi * 16 + row_base + r;
                size_t off = (size_t)row * Nn + col;
                float v = acc[mi][nj][r] + bv;
                outB[off] = f2b(EPI == 2 ? gelu_f(v) : v);
            }
        }
    }
}

// ---------- GEMM B: 32x32x16, 64x64 block, BK=128, dbuf (N=512 GEMMs) ----------
// EPI: 1 bias+residF32->bf16 | 3 bias+residB16->fp32 (d_out)
template <int EPI>
__global__ __launch_bounds__(256, 2) void gemm32(const u16* __restrict__ A,
                                                 const u16* __restrict__ W,
                                                 const float* __restrict__ bias,
                                                 const float* __restrict__ residF,
                                                 const u16* __restrict__ residB,
                                                 float* __restrict__ outF,
                                                 u16* __restrict__ outB,
                                                 int M, int Nn, int K) {
    constexpr int BM = 64, BN = 64, BK = 128;
    constexpr int CPR = BK / 8, KMSK = CPR - 1;
    __shared__ u16 a_s[2][BM * BK];
    __shared__ u16 b_s[2][BN * BK];

    int tid = threadIdx.x;
    int wid = tid >> 6, lane = tid & 63;
    int wm = wid >> 1, wn = wid & 1;
    int m_blk = blockIdx.x * BM;
    int n_blk = blockIdx.y * BN;
    int lr = lane & 31;
    int lk = lane >> 5;

    floatx16 acc;
    #pragma unroll
    for (int r = 0; r < 16; r++) acc[r] = 0.f;

    const u16* Ag = A + (size_t)m_blk * K;
    const u16* Wg = W + (size_t)n_blk * K;

    int srow = tid / CPR;                 // 4 rows per 64 threads
    int skc = (tid & KMSK) ^ (srow & KMSK);

    auto stage = [&](int k0, int buf) {
        #pragma unroll
        for (int p = 0; p < 4; p++)
            gl_lds16(Ag + (size_t)(p * 16 + srow) * K + k0 + skc * 8,
                     a_s[buf] + (p * 256 + tid) * 8);
        #pragma unroll
        for (int p = 0; p < 4; p++)
            gl_lds16(Wg + (size_t)(p * 16 + srow) * K + k0 + skc * 8,
                     b_s[buf] + (p * 256 + tid) * 8);
    };

    stage(0, 0);
    int nit = K / BK;
    for (int it = 0; it < nit; it++) {
        __syncthreads();
        if (it + 1 < nit) stage((it + 1) * BK, (it + 1) & 1);
        int cb = it & 1;
        #pragma unroll
        for (int s = 0; s < BK / 16; s++) {
            int kc = s * 2 + lk;
            int arow = wm * 32 + lr;
            int brow = wn * 32 + lr;
            shortx8 af = *(const shortx8*)(a_s[cb] + (arow * CPR + (kc ^ (arow & KMSK))) * 8);
            shortx8 bf = *(const shortx8*)(b_s[cb] + (brow * CPR + (kc ^ (brow & KMSK))) * 8);
            acc = __builtin_amdgcn_mfma_f32_32x32x16_bf16(af, bf, acc, 0, 0, 0);
        }
    }

    int col_l = lane & 31;
    int row_q = 4 * (lane >> 5);
    int col = n_blk + wn * 32 + col_l;
    float bv = bias[col];
    #pragma unroll
    for (int r = 0; r < 16; r++) {
        int row = m_blk + wm * 32 + (r & 3) + 8 * (r >> 2) + row_q;
        size_t off = (size_t)row * Nn + col;
        float v = acc[r] + bv;
        if (EPI == 1) outB[off] = f2b(v + residF[off]);
        else          outF[off] = v + b2f(residB[off]);
    }
}

// ---------- windowed attention, MFMA flash-style ----------
// LDS strides chosen for bank spread (word-stride mod 32):
//  k_s [76]: 38w = 6 mod 32 -> 16 distinct read start-banks (was 8)
//  v_t [154]: 77w/row; write rows 2j: 26j mod 32, gcd 2 -> 2-way (was 8-way)
//  p_s [106]: 53w = 21 mod 32, odd -> injective col spread on PV reads
// Grid tail blocks (bx >= 512) convert fc2 weights (overlap with attn).
__global__ __launch_bounds__(256) void attn_kernel(const u16* __restrict__ qkv,
                                                   const float* __restrict__ rel_bias,
                                                   u16* __restrict__ out,
                                                   const float* __restrict__ csrc,
                                                   u16* __restrict__ cdst) {
    __shared__ u16 k_s[128][76];
    __shared__ u16 v_t[64][154];
    __shared__ u16 p_s[4][16][106];
    __shared__ float s_bias[64];

    int bx = blockIdx.x;
    if (bx >= 512) {                      // weight-cvt tail (w2)
        cvt_block(csrc, cdst, bx - 512);
        return;
    }
    int n = bx >> 8;
    int h = (bx >> 5) & 7;
    int t0 = (bx & 31) << 6;
    int tid = threadIdx.x, wid = tid >> 6, lane = tid & 63;
    int col = lane & 15, rq = lane >> 4;

    const u16* qrow = qkv + (size_t)(n * 2048 + t0 + wid * 16 + col) * 1536 + h * 64 + rq * 8;
    shortx8 qf0 = *(const shortx8*)qrow;
    shortx8 qf1 = *(const shortx8*)(qrow + 32);

    if (tid < 63) s_bias[tid] = rel_bias[h * 63 + tid];
    if (tid == 63) s_bias[63] = 0.f;

    const uint* qkv_u = (const uint*)qkv;
    // K tile: vectorized uint2 loads (8B/lane), 8 iters
    for (int idx = tid; idx < 128 * 16; idx += 256) {
        int row = idx >> 4, j2 = idx & 15;
        int pos = t0 - 31 + row;
        uint2 kv; kv.x = 0u; kv.y = 0u;
        if (pos >= 0 && pos < 2048)
            kv = *(const uint2*)(qkv_u + (size_t)(n * 2048 + pos) * 768 + 256 + h * 32 + j2 * 2);
        *(uint2*)&k_s[row][j2 * 4] = kv;
    }
    // V transpose: row-pairs, packed b32 LDS writes
    for (int idx = tid; idx < 72 * 32; idx += 256) {
        int rp = idx >> 5, j = idx & 31;
        int r0 = rp * 2;
        int p0 = t0 - 31 + r0, p1 = p0 + 1;
        uint a = 0u, b = 0u;
        if (p0 >= 0 && p0 < 2048)
            a = qkv_u[(size_t)(n * 2048 + p0) * 768 + 512 + h * 32 + j];
        if (p1 >= 0 && p1 < 2048)
            b = qkv_u[(size_t)(n * 2048 + p1) * 768 + 512 + h * 32 + j];
        *(uint*)&v_t[2 * j][r0]     = (a & 0xffffu) | (b << 16);
        *(uint*)&v_t[2 * j + 1][r0] = (a >> 16) | (b & 0xffff0000u);
    }
    __syncthreads();

    floatx4 S[5];
    #pragma unroll
    for (int nt = 0; nt < 5; nt++) S[nt] = (floatx4){0.f, 0.f, 0.f, 0.f};
    #pragma unroll
    for (int nt = 0; nt < 5; nt++) {
        const u16* kb = &k_s[wid * 16 + nt * 16 + col][rq * 8];
        shortx8 b0 = *(const shortx8*)kb;
        shortx8 b1 = *(const shortx8*)(kb + 32);
        S[nt] = __builtin_amdgcn_mfma_f32_16x16x32_bf16(qf0, b0, S[nt], 0, 0, 0);
        S[nt] = __builtin_amdgcn_mfma_f32_16x16x32_bf16(qf1, b1, S[nt], 0, 0, 0);
    }

    #pragma unroll
    for (int r = 0; r < 4; r++) {
        int t_row = rq * 4 + r;
        float sc[5];
        float mx = -1e30f;
        #pragma unroll
        for (int nt = 0; nt < 5; nt++) {
            int w = nt * 16 + col - t_row;
            int pos_abs = t0 - 31 + wid * 16 + nt * 16 + col;
            float v;
            if (w < 0 || w > 62) {
                v = -1e30f;
            } else {
                v = S[nt][r] * 0.125f + s_bias[w];
                if (pos_abs < 0 || pos_abs >= 2048) v -= 100.f;
            }
            sc[nt] = v;
            mx = fmaxf(mx, v);
        }
        #pragma unroll
        for (int o = 1; o < 16; o <<= 1) mx = fmaxf(mx, __shfl_xor(mx, o, 64));
        float l = 0.f;
        #pragma unroll
        for (int nt = 0; nt < 5; nt++) {
            sc[nt] = __expf(sc[nt] - mx);
            l += sc[nt];
        }
        #pragma unroll
        for (int o = 1; o < 16; o <<= 1) l += __shfl_xor(l, o, 64);
        float inv = 1.0f / l;
        #pragma unroll
        for (int nt = 0; nt < 5; nt++)
            p_s[wid][t_row][nt * 16 + col] = f2b(sc[nt] * inv);
        p_s[wid][t_row][80 + col] = 0;
    }
    __syncthreads();

    floatx4 O[4];
    #pragma unroll
    for (int dt = 0; dt < 4; dt++) O[dt] = (floatx4){0.f, 0.f, 0.f, 0.f};
    const u16* pr = &p_s[wid][col][rq * 8];
    shortx8 a0 = *(const shortx8*)pr;
    shortx8 a1 = *(const shortx8*)(pr + 32);
    shortx8 a2 = *(const shortx8*)(pr + 64);
    #pragma unroll
    for (int dt = 0; dt < 4; dt++) {
        const u16* vb = &v_t[dt * 16 + col][wid * 16 + rq * 8];
        shortx8 b0 = *(const shortx8*)vb;
        shortx8 b1 = *(const shortx8*)(vb + 32);
        shortx8 b2 = *(const shortx8*)(vb + 64);
        O[dt] = __builtin_amdgcn_mfma_f32_16x16x32_bf16(a0, b0, O[dt], 0, 0, 0);
        O[dt] = __builtin_amdgcn_mfma_f32_16x16x32_bf16(a1, b1, O[dt], 0, 0, 0);
        O[dt] = __builtin_amdgcn_mfma_f32_16x16x32_bf16(a2, b2, O[dt], 0, 0, 0);
    }

    #pragma unroll
    for (int dt = 0; dt < 4; dt++) {
        #pragma unroll
        for (int r = 0; r < 4; r++) {
            int t_row = rq * 4 + r;
            out[(size_t)(n * 2048 + t0 + wid * 16 + t_row) * 512 + h * 64 + dt * 16 + col] =
                f2b(O[dt][r]);
        }
    }
}

// ---------- launcher ----------
extern "C" void kernel_launch(void* const* d_in, const int* in_sizes, int n_in,
                              void* d_out, int out_size, void* d_ws, size_t ws_size,
                              hipStream_t stream) {
    const float* x     = (const float*)d_in[0];
    const float* n1w   = (const float*)d_in[1];
    const float* n1b   = (const float*)d_in[2];
    const float* qkvw  = (const float*)d_in[3];
    const float* qkvbv = (const float*)d_in[4];
    const float* relb  = (const float*)d_in[5];
    const float* projw = (const float*)d_in[6];
    const float* projb = (const float*)d_in[7];
    const float* n2w   = (const float*)d_in[8];
    const float* n2b   = (const float*)d_in[9];
    const float* fc1w  = (const float*)d_in[10];
    const float* fc1b  = (const float*)d_in[11];
    const float* fc2w  = (const float*)d_in[12];
    const float* fc2b  = (const float*)d_in[13];
    float* out = (float*)d_out;

    char* p = (char*)d_ws;
    u16* wq   = (u16*)p;  p += (size_t)786432 * 2;   // qkv_w bf16 (1536x512)
    u16* wp   = (u16*)p;  p += (size_t)262144 * 2;   // proj_w bf16 (512x512)
    u16* w1   = (u16*)p;  p += (size_t)1048576 * 2;  // fc1_w bf16 (2048x512)
    u16* w2   = (u16*)p;  p += (size_t)1048576 * 2;  // fc2_w bf16 (512x2048)
    u16* hb   = (u16*)p;  p += (size_t)2097152 * 2;  // h / h2 bf16 (4096x512)
    u16* qkvb = (u16*)p;  p += (size_t)6291456 * 2;  // qkv bf16 (4096x1536)
    u16* attb = (u16*)p;  p += (size_t)2097152 * 2;  // attn out bf16 (4096x512)
    u16* x2b  = (u16*)p;  p += (size_t)2097152 * 2;  // x + proj(attn), bf16
    u16* mb   = (u16*)p;  p += (size_t)8388608 * 2;  // gelu(fc1) bf16 (4096x2048)

    // phase 0: wq cvt (768) + LN1 (1024)
    prep_kernel<<<1792, 256, 0, stream>>>(qkvw, wq, x, n1w, n1b, hb);
    // phase 1: qkv GEMM (32x12=384 blocks) + wp cvt (256) + w1 cvt (1024) tail
    gemm16<0><<<dim3(32, 12 + 40), 256, 0, stream>>>(hb, wq, qkvbv, qkvb,
                                                     4096, 1536, 512, 12,
                                                     projw, wp, 256,
                                                     fc1w, w1, 1024);
    // phase 2: attention (512 blocks) + w2 cvt (1024) tail
    attn_kernel<<<512 + 1024, 256, 0, stream>>>(qkvb, relb, attb, fc2w, w2);
    // phase 3: proj: x2 = x + proj (bf16)
    gemm32<1><<<dim3(64, 8), 256, 0, stream>>>(attb, wp, projb, x, nullptr,
                                               nullptr, x2b, 4096, 512, 512);
    // phase 4: LN2
    ln_kernel_b<<<1024, 256, 0, stream>>>(x2b, n2w, n2b, hb);
    // phase 5: fc1 + GELU
    gemm16<2><<<dim3(32, 16), 256, 0, stream>>>(hb, w1, fc1b, mb,
                                                4096, 2048, 512, 16,
                                                nullptr, nullptr, 0,
                                                nullptr, nullptr, 0);
    // phase 6: fc2: out = x2 + fc2 (fp32)
    gemm32<3><<<dim3(64, 8), 256, 0, stream>>>(mb, w2, fc2b, nullptr, x2b,
                                               out, nullptr, 4096, 512, 2048);
}